// Round 10
// baseline (45564.053 us; speedup 1.0000x reference)
//
#include <hip/hip_runtime.h>
#include <hip/hip_fp16.h>
#include <math.h>

#define F 8
#define T_IN 336
#define T_OUT 96
#define D_OUT 2
#define NGRP 16      // batch groups (16 rows each)
#define WPG 32       // workgroups per group (unit slices)
#define ROWS 16
#define NT 512
#define HROW 2048    // LDS hcat row stride bytes

// weight regions (shorts), kb-major tiled: [(s*4+w)][kb][lane(64)][8]
#define WE0 0
#define WE1 1048576
#define WD0 3145728
#define WD1 4194304
#define W_TOTAL 6291456
// tagged h-state: dword = [tag:16 | fp16:16]
#define HB_DW 131072   // dwords per buffer (256*512)

using f32x4 = __attribute__((ext_vector_type(4))) float;
using f16x8 = __attribute__((ext_vector_type(8))) _Float16;

struct Args {
  const float *src;
  const float *eWih0, *eb0, *eb1;
  const float *dWih0, *db0, *db1;
  const float *fcW, *fcb, *pW, *pb;
  const unsigned short *W;
  unsigned *Hst;     // tagged h-state dwords
  float *out;
  unsigned *cnt;     // per-group arrive counters
};

__device__ __forceinline__ float sigm(float x) { return 1.f / (1.f + __expf(-x)); }
__device__ __forceinline__ float tanh_f(float x) {
  float e = __expf(-2.f * fabsf(x));
  float r = (1.f - e) / (1.f + e);
  return copysignf(r, x);
}
__device__ __forceinline__ f32x4 mfma16(f16x8 a, f16x8 b, f32x4 c) {
  return __builtin_amdgcn_mfma_f32_16x16x32_f16(a, b, c, 0, 0, 0);
}
__device__ __forceinline__ void ld16_cg(uint4& d, const void* p) {
  asm volatile("global_load_dwordx4 %0, %1, off sc0 sc1" : "=v"(d) : "v"(p));
}
__device__ __forceinline__ void st4_cg(void* p, unsigned v) {
  asm volatile("global_store_dword %0, %1, off sc0 sc1" :: "v"(p), "v"(v) : "memory");
}
__device__ __forceinline__ unsigned packh(float h, unsigned tag) {
  return (tag << 16) | (unsigned)__half_as_ushort(__float2half_rn(h));
}
__device__ __forceinline__ unsigned pk2(unsigned a, unsigned b) {
  return (a & 0xffffu) | (b << 16);
}

// fp32 -> fp16, kb-major wave-fragment layout (identical to rounds 7-9)
__global__ __launch_bounds__(256) void conv_kernel(
    const float* eWhh0, const float* eWih1, const float* eWhh1,
    const float* dWhh0, const float* dWih1, const float* dWhh1,
    unsigned short* W) {
  size_t i = (size_t)blockIdx.x * 256 + threadIdx.x;
  if (i >= W_TOTAL) return;
  int set, j;
  if (i < WE1)      { set = 0; j = (int)i; }
  else if (i < WD0) { set = 1; j = (int)(i - WE1); }
  else if (i < WD1) { set = 2; j = (int)(i - WD0); }
  else              { set = 3; j = (int)(i - WD1); }
  const int big = (set == 1 || set == 3);
  const int e = j & 7, lane = (j >> 3) & 63, r = j >> 9;
  const int kb = big ? (r & 31) : (r & 15);
  const int sw = big ? (r >> 5) : (r >> 4);
  const int s = sw >> 2, w = sw & 3;
  const int c = lane & 15;
  const int n = (c & 3) * 512 + 16 * s + 4 * w + (c >> 2);
  const int k = kb * 32 + (lane >> 4) * 8 + e;
  float v;
  if (set == 0)      v = eWhh0[(size_t)n * 512 + k];
  else if (set == 1) v = (k < 512) ? eWih1[(size_t)n * 512 + k] : eWhh1[(size_t)n * 512 + k - 512];
  else if (set == 2) v = dWhh0[(size_t)n * 512 + k];
  else               v = (k < 512) ? dWih1[(size_t)n * 512 + k] : dWhh1[(size_t)n * 512 + k - 512];
  W[i] = __half_as_ushort(__float2half_rn(v));
}

__global__ __launch_bounds__(NT, 4) void forecast_kernel(Args a) {
  extern __shared__ char smem[];
  char* HC = smem;                           // [16][2048B] fp16 hcat, XOR-swizzled
  float* TT = (float*)(smem + ROWS * HROW);  // [8 waves][16][18]
  float* p_lds = TT + 8 * 288;               // [32]
  float* x_lds = p_lds + 32;                 // [16][9]
  float* WxL = x_lds + 144;                  // [2 sets][64 rows][9]
  float* bL = WxL + 1152;                    // [4 sets][4 gates][16 units]
  float* pWb = bL + 256;                     // pW[16], pb[8], fcb[2]

  const int tid = threadIdx.x;
  const int g = blockIdx.x >> 5;
  const int s = blockIdx.x & 31;
  const int lane = tid & 63, wid = tid >> 6;
  const int bb = lane & 15;
  const int lq = lane >> 4;
  const int isL0 = (wid < 4);
  const int w4 = isL0 ? wid : wid - 4;
  const int uu = lane >> 4;
  const int unitL = w4 * 4 + uu;
  const int rowG = 16 * g + bb;
  float* TTw = TT + wid * 288;
  unsigned* cnt = a.cnt + g * 32;

  unsigned* H0 = a.Hst;
  unsigned* H1 = a.Hst + 2 * HB_DW;

  const int nkbE = isL0 ? 16 : 32;
  const unsigned short* wE = a.W + (isL0 ? WE0 : WE1) + (size_t)(s * 4 + w4) * nkbE * 512 + lane * 8;
  const unsigned short* wD = a.W + (isL0 ? WD0 : WD1) + (size_t)(s * 4 + w4) * nkbE * 512 + lane * 8;

  for (int e = tid; e < 1152; e += NT) {
    int set = e / 576, e2 = e % 576, row = e2 / 9, k = e2 % 9;
    const float* sw = set ? a.dWih0 : a.eWih0;
    WxL[e] = (k < 8) ? sw[(size_t)((row >> 4) * 512 + 16 * s + (row & 15)) * 8 + k] : 0.f;
  }
  if (tid < 256) {
    int bs = tid >> 6, q = (tid >> 4) & 3, u2 = tid & 15;
    const float* sp = bs == 0 ? a.eb0 : bs == 1 ? a.eb1 : bs == 2 ? a.db0 : a.db1;
    bL[tid] = sp[q * 512 + 16 * s + u2];
  }
  if (tid < 16) pWb[tid] = a.pW[tid];
  else if (tid < 24) pWb[tid] = a.pb[tid - 16];
  else if (tid < 26) pWb[tid] = a.fcb[tid - 24];
  __syncthreads();

  float c01 = 0.f;
  const int srow = tid >> 5, seg = tid & 31;
  const int wswz = (srow & 7) << 4;
  const int aswz = (bb & 7) << 4;

  // fallback spin on group counter (proven primitive; lane0 per wave)
  auto cwait = [&](unsigned tgt) {
    if (lane == 0) {
      long gd = 0;
      while (__hip_atomic_load(cnt, __ATOMIC_RELAXED, __HIP_MEMORY_SCOPE_AGENT) < tgt) {
        __builtin_amdgcn_s_sleep(2);
        if (++gd > (1L << 19)) break;
      }
    }
  };
  // arrive: release stores, then one add per WG
  auto arrive = [&]() {
    asm volatile("s_waitcnt vmcnt(0)" ::: "memory");
    __syncthreads();
    if (tid == 0)
      __hip_atomic_fetch_add(cnt, 1u, __ATOMIC_RELAXED, __HIP_MEMORY_SCOPE_AGENT);
  };

  // tag-validated staging of both planes; counter fallback; strip tags into LDS
  auto stage2 = [&](const unsigned* b0, const unsigned* b1, unsigned ex0, unsigned ex1, unsigned tgt) {
    const unsigned* p0 = b0 + (size_t)(16 * g + srow) * 512 + seg * 16;
    const unsigned* p1 = b1 + (size_t)(16 * g + srow) * 512 + seg * 16;
    uint4 q[8];
    bool good = false;
    for (int it = 0; it < 16; ++it) {
      ld16_cg(q[0], p0);  ld16_cg(q[1], p0 + 4);  ld16_cg(q[2], p0 + 8);  ld16_cg(q[3], p0 + 12);
      ld16_cg(q[4], p1);  ld16_cg(q[5], p1 + 4);  ld16_cg(q[6], p1 + 8);  ld16_cg(q[7], p1 + 12);
      asm volatile("s_waitcnt vmcnt(0)" ::: "memory");
      __builtin_amdgcn_sched_barrier(0);
      bool ok = true;
      #pragma unroll
      for (int i = 0; i < 4; ++i)
        ok = ok && (q[i].x >> 16) == ex0 && (q[i].y >> 16) == ex0 &&
                   (q[i].z >> 16) == ex0 && (q[i].w >> 16) == ex0;
      #pragma unroll
      for (int i = 4; i < 8; ++i)
        ok = ok && (q[i].x >> 16) == ex1 && (q[i].y >> 16) == ex1 &&
                   (q[i].z >> 16) == ex1 && (q[i].w >> 16) == ex1;
      good = ok;
      if (__all(ok)) break;
      __builtin_amdgcn_s_sleep(1);
    }
    if (!__all(good)) {
      cwait(tgt);   // proven counter barrier; then one coherent reload
      ld16_cg(q[0], p0);  ld16_cg(q[1], p0 + 4);  ld16_cg(q[2], p0 + 8);  ld16_cg(q[3], p0 + 12);
      ld16_cg(q[4], p1);  ld16_cg(q[5], p1 + 4);  ld16_cg(q[6], p1 + 8);  ld16_cg(q[7], p1 + 12);
      asm volatile("s_waitcnt vmcnt(0)" ::: "memory");
      __builtin_amdgcn_sched_barrier(0);
    }
    char* dr = HC + srow * HROW;
    uint4 w0 = {pk2(q[0].x,q[0].y), pk2(q[0].z,q[0].w), pk2(q[1].x,q[1].y), pk2(q[1].z,q[1].w)};
    uint4 w1 = {pk2(q[2].x,q[2].y), pk2(q[2].z,q[2].w), pk2(q[3].x,q[3].y), pk2(q[3].z,q[3].w)};
    uint4 w2 = {pk2(q[4].x,q[4].y), pk2(q[4].z,q[4].w), pk2(q[5].x,q[5].y), pk2(q[5].z,q[5].w)};
    uint4 w3 = {pk2(q[6].x,q[6].y), pk2(q[6].z,q[6].w), pk2(q[7].x,q[7].y), pk2(q[7].z,q[7].w)};
    *(uint4*)(dr + ((seg * 32) ^ wswz))             = w0;
    *(uint4*)(dr + ((seg * 32 + 16) ^ wswz))        = w1;
    *(uint4*)(dr + 1024 + ((seg * 32) ^ wswz))      = w2;
    *(uint4*)(dr + 1024 + ((seg * 32 + 16) ^ wswz)) = w3;
  };
  auto stage1 = [&](const unsigned* b0, int plane, unsigned ex0, unsigned tgt) {
    const unsigned* p0 = b0 + (size_t)(16 * g + srow) * 512 + seg * 16;
    uint4 q[4];
    bool good = false;
    for (int it = 0; it < 16; ++it) {
      ld16_cg(q[0], p0);  ld16_cg(q[1], p0 + 4);  ld16_cg(q[2], p0 + 8);  ld16_cg(q[3], p0 + 12);
      asm volatile("s_waitcnt vmcnt(0)" ::: "memory");
      __builtin_amdgcn_sched_barrier(0);
      bool ok = true;
      #pragma unroll
      for (int i = 0; i < 4; ++i)
        ok = ok && (q[i].x >> 16) == ex0 && (q[i].y >> 16) == ex0 &&
                   (q[i].z >> 16) == ex0 && (q[i].w >> 16) == ex0;
      good = ok;
      if (__all(ok)) break;
      __builtin_amdgcn_s_sleep(1);
    }
    if (!__all(good)) {
      cwait(tgt);
      ld16_cg(q[0], p0);  ld16_cg(q[1], p0 + 4);  ld16_cg(q[2], p0 + 8);  ld16_cg(q[3], p0 + 12);
      asm volatile("s_waitcnt vmcnt(0)" ::: "memory");
      __builtin_amdgcn_sched_barrier(0);
    }
    char* dr = HC + srow * HROW + plane;
    uint4 w0 = {pk2(q[0].x,q[0].y), pk2(q[0].z,q[0].w), pk2(q[1].x,q[1].y), pk2(q[1].z,q[1].w)};
    uint4 w1 = {pk2(q[2].x,q[2].y), pk2(q[2].z,q[2].w), pk2(q[3].x,q[3].y), pk2(q[3].z,q[3].w)};
    *(uint4*)(dr + ((seg * 32) ^ wswz))      = w0;
    *(uint4*)(dr + ((seg * 32 + 16) ^ wswz)) = w1;
  };
  auto fcwave = [&](int t, bool writeOut) {   // wave 4: pred + x for 16 rows
    const int pb_ = lane & 15, dd = (lane >> 4) & 1, hf = lane >> 5;
    const char* hp = HC + pb_ * HROW;
    const int fswz = (pb_ & 7) << 4;
    const float* wr = a.fcW + dd * 512 + hf * 256;
    float r = 0.f;
    #pragma unroll 8
    for (int j = 0; j < 32; ++j) {
      f16x8 v = *(const f16x8*)(hp + ((1024 + hf * 512 + j * 16) ^ fswz));
      float4 w0 = *(const float4*)(wr + j * 8);
      float4 w1 = *(const float4*)(wr + j * 8 + 4);
      r = fmaf((float)v[0], w0.x, r); r = fmaf((float)v[1], w0.y, r);
      r = fmaf((float)v[2], w0.z, r); r = fmaf((float)v[3], w0.w, r);
      r = fmaf((float)v[4], w1.x, r); r = fmaf((float)v[5], w1.y, r);
      r = fmaf((float)v[6], w1.z, r); r = fmaf((float)v[7], w1.w, r);
    }
    r += __shfl_xor(r, 32);
    if (lane < 32) {
      float pred = r + pWb[24 + dd];
      if (t == 0) pred = a.src[(size_t)(16 * g + pb_) * (T_IN * F) + 335 * F + dd * 2];
      p_lds[pb_ * 2 + dd] = pred;
      if (writeOut && s == 0 && t > 0)
        a.out[(size_t)(16 * g + pb_) * (T_OUT * D_OUT) + (size_t)(t - 1) * D_OUT + dd] = pred;
    }
    const int bx = lane >> 2, j0 = (lane & 3) * 2;
    float pr0 = p_lds[bx * 2], pr1 = p_lds[bx * 2 + 1];
    x_lds[bx * 9 + j0]     = pWb[16 + j0]     + pr0 * pWb[j0 * 2]       + pr1 * pWb[j0 * 2 + 1];
    x_lds[bx * 9 + j0 + 1] = pWb[16 + j0 + 1] + pr0 * pWb[(j0 + 1) * 2] + pr1 * pWb[(j0 + 1) * 2 + 1];
  };

  // ================= encoder =================
  for (int t = 0; t <= T_IN; ++t) {
    const int buf = t & 1, nbuf = buf ^ 1;
    stage2(H0 + (size_t)buf * HB_DW, H1 + (size_t)buf * HB_DW,
           (unsigned)t, (unsigned)(t <= 1 ? 0 : t), (unsigned)t * 32u);
    __syncthreads();
    const bool active = isL0 ? (t < T_IN) : (t >= 1);
    if (active) {
      f32x4 acc = {0.f, 0.f, 0.f, 0.f};
      const char* arow = HC + bb * HROW;
      for (int kb = 0; kb < nkbE; ++kb)
        acc = mfma16(*(const f16x8*)(arow + ((lq * 16 + kb * 64) ^ aswz)),
                     *(const f16x8*)(wE + (size_t)kb * 512), acc);
      #pragma unroll
      for (int j = 0; j < 4; ++j) TTw[bb * 18 + lq * 4 + j] = acc[j];
      float ac[4];
      #pragma unroll
      for (int q = 0; q < 4; ++q)
        ac[q] = TTw[(4 * uu + q) * 18 + bb] + bL[(isL0 ? 0 : 64) + q * 16 + unitL];
      if (isL0) {
        const float* xr = a.src + (size_t)rowG * (T_IN * F) + t * F;
        float4 x0 = *(const float4*)xr, x1 = *(const float4*)(xr + 4);
        float xv[8] = {x0.x, x0.y, x0.z, x0.w, x1.x, x1.y, x1.z, x1.w};
        #pragma unroll
        for (int q = 0; q < 4; ++q)
          #pragma unroll
          for (int k = 0; k < 8; ++k)
            ac[q] = fmaf(xv[k], WxL[(q * 16 + unitL) * 9 + k], ac[q]);
      }
      c01 = sigm(ac[1]) * c01 + sigm(ac[0]) * tanh_f(ac[2]);
      float h = sigm(ac[3]) * tanh_f(c01);
      unsigned* hplane = (isL0 ? H0 : H1) + (size_t)nbuf * HB_DW;
      st4_cg((void*)(hplane + (size_t)rowG * 512 + 16 * s + unitL), packh(h, (unsigned)(t + 1)));
    }
    arrive();
  }

  // ================= decoder =================
  for (int t = 0; t < T_OUT; ++t) {
    const int pA = t & 1;
    stage2(H0 + (size_t)pA * HB_DW, H1 + (size_t)(pA ^ 1) * HB_DW,
           (unsigned)(336 + 2 * t), (unsigned)(337 + 2 * t), (unsigned)(337 + 2 * t) * 32u);
    __syncthreads();
    if (isL0) {  // D0 gate MFMAs
      f32x4 acc = {0.f, 0.f, 0.f, 0.f};
      const char* arow = HC + bb * HROW;
      for (int kb = 0; kb < 16; ++kb)
        acc = mfma16(*(const f16x8*)(arow + ((lq * 16 + kb * 64) ^ aswz)),
                     *(const f16x8*)(wD + (size_t)kb * 512), acc);
      #pragma unroll
      for (int j = 0; j < 4; ++j) TTw[bb * 18 + lq * 4 + j] = acc[j];
    } else if (wid == 4) {
      fcwave(t, true);
    }
    __syncthreads();
    if (isL0) {  // c0 update with x -> h0(t) tag 338+2t
      float ac[4];
      #pragma unroll
      for (int q = 0; q < 4; ++q)
        ac[q] = TTw[(4 * uu + q) * 18 + bb] + bL[128 + q * 16 + unitL];
      #pragma unroll
      for (int q = 0; q < 4; ++q)
        #pragma unroll
        for (int k = 0; k < 8; ++k)
          ac[q] = fmaf(x_lds[bb * 9 + k], WxL[576 + (q * 16 + unitL) * 9 + k], ac[q]);
      c01 = sigm(ac[1]) * c01 + sigm(ac[0]) * tanh_f(ac[2]);
      float h = sigm(ac[3]) * tanh_f(c01);
      unsigned* hplane = H0 + (size_t)(pA ^ 1) * HB_DW;
      st4_cg((void*)(hplane + (size_t)rowG * 512 + 16 * s + unitL), packh(h, (unsigned)(338 + 2 * t)));
    }
    arrive();  // phase A arrive
    stage1(H0 + (size_t)(pA ^ 1) * HB_DW, 0, (unsigned)(338 + 2 * t), (unsigned)(338 + 2 * t) * 32u);
    __syncthreads();
    if (!isL0) {  // D1 gates + c1 update -> h1(t) tag 339+2t
      f32x4 acc = {0.f, 0.f, 0.f, 0.f};
      const char* arow = HC + bb * HROW;
      for (int kb = 0; kb < 32; ++kb)
        acc = mfma16(*(const f16x8*)(arow + ((lq * 16 + kb * 64) ^ aswz)),
                     *(const f16x8*)(wD + (size_t)kb * 512), acc);
      #pragma unroll
      for (int j = 0; j < 4; ++j) TTw[bb * 18 + lq * 4 + j] = acc[j];
      float ac[4];
      #pragma unroll
      for (int q = 0; q < 4; ++q)
        ac[q] = TTw[(4 * uu + q) * 18 + bb] + bL[192 + q * 16 + unitL];
      c01 = sigm(ac[1]) * c01 + sigm(ac[0]) * tanh_f(ac[2]);
      float h = sigm(ac[3]) * tanh_f(c01);
      unsigned* hplane = H1 + (size_t)pA * HB_DW;
      st4_cg((void*)(hplane + (size_t)rowG * 512 + 16 * s + unitL), packh(h, (unsigned)(339 + 2 * t)));
    }
    arrive();  // phase B arrive
  }

  // ================= epilogue: pred(95), h1 in buf 1 tag 529 =================
  stage1(H1 + (size_t)1 * HB_DW, 1024, 529u, 529u * 32u);
  __syncthreads();
  if (wid == 4 && s == 0) {
    const int pb_ = lane & 15, dd = (lane >> 4) & 1, hf = lane >> 5;
    const char* hp = HC + pb_ * HROW;
    const int fswz = (pb_ & 7) << 4;
    const float* wr = a.fcW + dd * 512 + hf * 256;
    float r = 0.f;
    #pragma unroll 8
    for (int j = 0; j < 32; ++j) {
      f16x8 v = *(const f16x8*)(hp + ((1024 + hf * 512 + j * 16) ^ fswz));
      float4 w0 = *(const float4*)(wr + j * 8);
      float4 w1 = *(const float4*)(wr + j * 8 + 4);
      r = fmaf((float)v[0], w0.x, r); r = fmaf((float)v[1], w0.y, r);
      r = fmaf((float)v[2], w0.z, r); r = fmaf((float)v[3], w0.w, r);
      r = fmaf((float)v[4], w1.x, r); r = fmaf((float)v[5], w1.y, r);
      r = fmaf((float)v[6], w1.z, r); r = fmaf((float)v[7], w1.w, r);
    }
    r += __shfl_xor(r, 32);
    if (lane < 32)
      a.out[(size_t)(16 * g + pb_) * (T_OUT * D_OUT) + (size_t)95 * D_OUT + dd] = r + pWb[24 + dd];
  }
}

extern "C" void kernel_launch(void* const* d_in, const int* in_sizes, int n_in,
                              void* d_out, int out_size, void* d_ws, size_t ws_size,
                              hipStream_t stream) {
  (void)in_sizes; (void)n_in; (void)out_size; (void)ws_size;
  const float* src   = (const float*)d_in[0];
  const float* eWih0 = (const float*)d_in[1];
  const float* eWhh0 = (const float*)d_in[2];
  const float* eb0   = (const float*)d_in[3];
  const float* eWih1 = (const float*)d_in[4];
  const float* eWhh1 = (const float*)d_in[5];
  const float* eb1   = (const float*)d_in[6];
  const float* dWih0 = (const float*)d_in[7];
  const float* dWhh0 = (const float*)d_in[8];
  const float* db0   = (const float*)d_in[9];
  const float* dWih1 = (const float*)d_in[10];
  const float* dWhh1 = (const float*)d_in[11];
  const float* db1   = (const float*)d_in[12];
  const float* fcW   = (const float*)d_in[13];
  const float* fcb   = (const float*)d_in[14];
  const float* pW    = (const float*)d_in[15];
  const float* pb    = (const float*)d_in[16];

  unsigned char* ws = (unsigned char*)d_ws;
  unsigned* cnt = (unsigned*)ws;                           // 4 KB counters
  unsigned short* W = (unsigned short*)(ws + 4096);        // 12.6 MB fp16 tiled weights
  unsigned* Hst = (unsigned*)(ws + 4096 + (size_t)W_TOTAL * 2);  // 2 MB tagged h-state

  (void)hipMemsetAsync(d_ws, 0, 4096, stream);
  (void)hipMemsetAsync((void*)Hst, 0, (size_t)4 * HB_DW * sizeof(unsigned), stream);

  hipLaunchKernelGGL(conv_kernel, dim3(W_TOTAL / 256), dim3(256), 0, stream,
                     eWhh0, eWih1, eWhh1, dWhh0, dWih1, dWhh1, W);

  Args a;
  a.src = src; a.eWih0 = eWih0; a.eb0 = eb0; a.eb1 = eb1;
  a.dWih0 = dWih0; a.db0 = db0; a.db1 = db1;
  a.fcW = fcW; a.fcb = fcb; a.pW = pW; a.pb = pb;
  a.W = W; a.Hst = Hst; a.out = (float*)d_out; a.cnt = cnt;

  // LDS: 32768 (HC) + (2304 + 32 + 144 + 1152 + 256 + 32)*4 = 48448 B
  const size_t smem_bytes = (size_t)ROWS * HROW + (2304 + 32 + 144 + 1152 + 256 + 32) * sizeof(float);
  hipLaunchKernelGGL(forecast_kernel, dim3(NGRP * WPG), dim3(NT), smem_bytes, stream, a);
}

// Round 11
// 5128.433 us; speedup vs baseline: 8.8846x; 8.8846x over previous
//
#include <hip/hip_runtime.h>
#include <hip/hip_fp16.h>
#include <math.h>

#define F 8
#define T_IN 336
#define T_OUT 96
#define D_OUT 2
#define NGRP 16      // batch groups (16 rows each)
#define WPG 32       // workgroups per group (unit slices)
#define ROWS 16
#define NT 512
#define HROW 2048    // LDS hcat row stride bytes

// weight regions (shorts), kb-major tiled: [(s*4+w)][kb][lane(64)][8]
#define WE0 0
#define WE1 1048576
#define WD0 3145728
#define WD1 4194304
#define W_TOTAL 6291456
// h-state planes (shorts)
#define HO0 0
#define HO1 262144
#define HBUF 131072

using f32x4 = __attribute__((ext_vector_type(4))) float;
using f16x8 = __attribute__((ext_vector_type(8))) _Float16;

struct Args {
  const float *src;
  const float *eWih0, *eb0, *eb1;
  const float *dWih0, *db0, *db1;
  const float *fcW, *fcb, *pW, *pb;
  const unsigned short *W;
  unsigned short *Hst;
  float *out;
  unsigned *cnt;     // [NGRP][32] slot barrier
};

__device__ __forceinline__ float sigm(float x) { return 1.f / (1.f + __expf(-x)); }
__device__ __forceinline__ float tanh_f(float x) {
  float e = __expf(-2.f * fabsf(x));
  float r = (1.f - e) / (1.f + e);
  return copysignf(r, x);
}
__device__ __forceinline__ f32x4 mfma16(f16x8 a, f16x8 b, f32x4 c) {
  return __builtin_amdgcn_mfma_f32_16x16x32_f16(a, b, c, 0, 0, 0);
}
__device__ __forceinline__ void ld16_cg(uint4& d, const void* p) {
  asm volatile("global_load_dwordx4 %0, %1, off sc0 sc1" : "=v"(d) : "v"(p));
}
__device__ __forceinline__ void st2_cg(void* p, unsigned v) {
  asm volatile("global_store_short %0, %1, off sc0 sc1" :: "v"(p), "v"(v) : "memory");
}

// fp32 -> fp16, kb-major wave-fragment layout (identical to round 7)
__global__ __launch_bounds__(256) void conv_kernel(
    const float* eWhh0, const float* eWih1, const float* eWhh1,
    const float* dWhh0, const float* dWih1, const float* dWhh1,
    unsigned short* W) {
  size_t i = (size_t)blockIdx.x * 256 + threadIdx.x;
  if (i >= W_TOTAL) return;
  int set, j;
  if (i < WE1)      { set = 0; j = (int)i; }
  else if (i < WD0) { set = 1; j = (int)(i - WE1); }
  else if (i < WD1) { set = 2; j = (int)(i - WD0); }
  else              { set = 3; j = (int)(i - WD1); }
  const int big = (set == 1 || set == 3);
  const int e = j & 7, lane = (j >> 3) & 63, r = j >> 9;
  const int kb = big ? (r & 31) : (r & 15);
  const int sw = big ? (r >> 5) : (r >> 4);
  const int s = sw >> 2, w = sw & 3;
  const int c = lane & 15;
  const int n = (c & 3) * 512 + 16 * s + 4 * w + (c >> 2);
  const int k = kb * 32 + (lane >> 4) * 8 + e;
  float v;
  if (set == 0)      v = eWhh0[(size_t)n * 512 + k];
  else if (set == 1) v = (k < 512) ? eWih1[(size_t)n * 512 + k] : eWhh1[(size_t)n * 512 + k - 512];
  else if (set == 2) v = dWhh0[(size_t)n * 512 + k];
  else               v = (k < 512) ? dWih1[(size_t)n * 512 + k] : dWhh1[(size_t)n * 512 + k - 512];
  W[i] = __half_as_ushort(__float2half_rn(v));
}

__global__ __launch_bounds__(NT, 4) void forecast_kernel(Args a) {
  extern __shared__ char smem[];
  char* HC = smem;                           // [16][2048B] fp16 hcat, XOR-swizzled
  float* TT = (float*)(smem + ROWS * HROW);  // [8 waves][16][18]
  float* p_lds = TT + 8 * 288;               // [32]
  float* x_lds = p_lds + 32;                 // [16][9]
  float* WxL = x_lds + 144;                  // [2 sets][64 rows][9]
  float* bL = WxL + 1152;                    // [4 sets][4 gates][16 units]
  float* pWb = bL + 256;                     // pW[16], pb[8], fcb[2]

  const int tid = threadIdx.x;
  const int g = blockIdx.x >> 5;
  const int s = blockIdx.x & 31;
  const int lane = tid & 63, wid = tid >> 6;
  const int bb = lane & 15;
  const int lq = lane >> 4;
  const int isL0 = (wid < 4);
  const int w4 = isL0 ? wid : wid - 4;
  const int uu = lane >> 4;
  const int unitL = w4 * 4 + uu;
  const int rowG = 16 * g + bb;
  float* TTw = TT + wid * 288;
  unsigned* slots = a.cnt + g * 32;
  unsigned bstage = 0;

  const int nkbE = isL0 ? 16 : 32;
  const unsigned short* wE = a.W + (isL0 ? WE0 : WE1) + (size_t)(s * 4 + w4) * nkbE * 512 + lane * 8;
  const unsigned short* wD = a.W + (isL0 ? WD0 : WD1) + (size_t)(s * 4 + w4) * nkbE * 512 + lane * 8;

  for (int e = tid; e < 1152; e += NT) {
    int set = e / 576, e2 = e % 576, row = e2 / 9, k = e2 % 9;
    const float* sw = set ? a.dWih0 : a.eWih0;
    WxL[e] = (k < 8) ? sw[(size_t)((row >> 4) * 512 + 16 * s + (row & 15)) * 8 + k] : 0.f;
  }
  if (tid < 256) {
    int bs = tid >> 6, q = (tid >> 4) & 3, u2 = tid & 15;
    const float* sp = bs == 0 ? a.eb0 : bs == 1 ? a.eb1 : bs == 2 ? a.db0 : a.db1;
    bL[tid] = sp[q * 512 + 16 * s + u2];
  }
  if (tid < 16) pWb[tid] = a.pW[tid];
  else if (tid < 24) pWb[tid] = a.pb[tid - 16];
  else if (tid < 26) pWb[tid] = a.fcb[tid - 24];
  __syncthreads();

  float c01 = 0.f;
  const int srow = tid >> 5, seg = tid & 31;
  const int wswz = (srow & 7) << 4;
  const int aswz = (bb & 7) << 4;

  // distributed slot barrier: store own stage (no atomics), wave0 lane-parallel poll
  auto gbar = [&]() {
    const unsigned stage = ++bstage;
    asm volatile("s_waitcnt vmcnt(0)" ::: "memory");   // drain sc stores
    __syncthreads();                                   // all waves arrived
    if (tid == 0)
      __hip_atomic_store(slots + s, stage, __ATOMIC_RELAXED, __HIP_MEMORY_SCOPE_AGENT);
    if (wid == 0) {
      long gd = 0;
      for (;;) {
        unsigned v = (lane < 32 && lane != s)
            ? __hip_atomic_load(slots + lane, __ATOMIC_RELAXED, __HIP_MEMORY_SCOPE_AGENT)
            : stage;
        if (__all((int)(v >= stage))) break;
        __builtin_amdgcn_s_sleep(1);
        if (++gd > (1L << 22)) break;
      }
    }
    __syncthreads();
    asm volatile("" ::: "memory");
  };

  auto stage2 = [&](const unsigned short* b0, const unsigned short* b1) {
    const unsigned short* p0 = b0 + (size_t)(16 * g + srow) * 512 + seg * 8;
    const unsigned short* p1 = b1 + (size_t)(16 * g + srow) * 512 + seg * 8;
    uint4 q0, q1, q2, q3;
    ld16_cg(q0, p0); ld16_cg(q1, p0 + 256); ld16_cg(q2, p1); ld16_cg(q3, p1 + 256);
    asm volatile("s_waitcnt vmcnt(0)" ::: "memory");
    __builtin_amdgcn_sched_barrier(0);
    char* d = HC + srow * HROW + ((seg * 16) ^ wswz);
    *(uint4*)d = q0; *(uint4*)(d + 512) = q1;
    *(uint4*)(d + 1024) = q2; *(uint4*)(d + 1536) = q3;
  };
  auto stage1 = [&](const unsigned short* b0, int plane) {
    const unsigned short* p0 = b0 + (size_t)(16 * g + srow) * 512 + seg * 8;
    uint4 q0, q1;
    ld16_cg(q0, p0); ld16_cg(q1, p0 + 256);
    asm volatile("s_waitcnt vmcnt(0)" ::: "memory");
    __builtin_amdgcn_sched_barrier(0);
    char* d = HC + srow * HROW + plane + ((seg * 16) ^ wswz);
    *(uint4*)d = q0; *(uint4*)(d + 512) = q1;
  };
  auto fcwave = [&](int t, bool writeOut) {   // wave 4: pred + x for 16 rows
    const int pb_ = lane & 15, dd = (lane >> 4) & 1, hf = lane >> 5;
    const char* hp = HC + pb_ * HROW;
    const int fswz = (pb_ & 7) << 4;
    const float* wr = a.fcW + dd * 512 + hf * 256;
    float r = 0.f;
    #pragma unroll 8
    for (int j = 0; j < 32; ++j) {
      f16x8 v = *(const f16x8*)(hp + ((1024 + hf * 512 + j * 16) ^ fswz));
      float4 w0 = *(const float4*)(wr + j * 8);
      float4 w1 = *(const float4*)(wr + j * 8 + 4);
      r = fmaf((float)v[0], w0.x, r); r = fmaf((float)v[1], w0.y, r);
      r = fmaf((float)v[2], w0.z, r); r = fmaf((float)v[3], w0.w, r);
      r = fmaf((float)v[4], w1.x, r); r = fmaf((float)v[5], w1.y, r);
      r = fmaf((float)v[6], w1.z, r); r = fmaf((float)v[7], w1.w, r);
    }
    r += __shfl_xor(r, 32);
    if (lane < 32) {
      float pred = r + pWb[24 + dd];
      if (t == 0) pred = a.src[(size_t)(16 * g + pb_) * (T_IN * F) + 335 * F + dd * 2];
      p_lds[pb_ * 2 + dd] = pred;
      if (writeOut && s == 0 && t > 0)
        a.out[(size_t)(16 * g + pb_) * (T_OUT * D_OUT) + (size_t)(t - 1) * D_OUT + dd] = pred;
    }
    const int bx = lane >> 2, j0 = (lane & 3) * 2;
    float pr0 = p_lds[bx * 2], pr1 = p_lds[bx * 2 + 1];
    x_lds[bx * 9 + j0]     = pWb[16 + j0]     + pr0 * pWb[j0 * 2]       + pr1 * pWb[j0 * 2 + 1];
    x_lds[bx * 9 + j0 + 1] = pWb[16 + j0 + 1] + pr0 * pWb[(j0 + 1) * 2] + pr1 * pWb[(j0 + 1) * 2 + 1];
  };

  // ================= encoder =================
  for (int t = 0; t <= T_IN; ++t) {
    const int buf = t & 1, nbuf = buf ^ 1;
    stage2(a.Hst + HO0 + (size_t)buf * HBUF, a.Hst + HO1 + (size_t)buf * HBUF);
    __syncthreads();
    const bool active = isL0 ? (t < T_IN) : (t >= 1);
    if (active) {
      f32x4 acc = {0.f, 0.f, 0.f, 0.f};
      const char* arow = HC + bb * HROW;
      for (int kb = 0; kb < nkbE; ++kb)
        acc = mfma16(*(const f16x8*)(arow + ((lq * 16 + kb * 64) ^ aswz)),
                     *(const f16x8*)(wE + (size_t)kb * 512), acc);
      #pragma unroll
      for (int j = 0; j < 4; ++j) TTw[bb * 18 + lq * 4 + j] = acc[j];
      float ac[4];
      #pragma unroll
      for (int q = 0; q < 4; ++q)
        ac[q] = TTw[(4 * uu + q) * 18 + bb] + bL[(isL0 ? 0 : 64) + q * 16 + unitL];
      if (isL0) {
        const float* xr = a.src + (size_t)rowG * (T_IN * F) + t * F;
        float4 x0 = *(const float4*)xr, x1 = *(const float4*)(xr + 4);
        float xv[8] = {x0.x, x0.y, x0.z, x0.w, x1.x, x1.y, x1.z, x1.w};
        #pragma unroll
        for (int q = 0; q < 4; ++q)
          #pragma unroll
          for (int k = 0; k < 8; ++k)
            ac[q] = fmaf(xv[k], WxL[(q * 16 + unitL) * 9 + k], ac[q]);
      }
      c01 = sigm(ac[1]) * c01 + sigm(ac[0]) * tanh_f(ac[2]);
      float h = sigm(ac[3]) * tanh_f(c01);
      unsigned short* hplane = a.Hst + (isL0 ? HO0 : HO1) + (size_t)nbuf * HBUF;
      st2_cg((void*)(hplane + (size_t)rowG * 512 + 16 * s + unitL),
             (unsigned)__half_as_ushort(__float2half_rn(h)));
    }
    gbar();
  }

  // ================= decoder =================
  // invariant: LDS plane 0 holds h0(t-1) on entry to phase A (from encoder-final
  // staging at t=0, or previous phase-B stage1 for t>0) -> phase A stages h1 only.
  for (int t = 0; t < T_OUT; ++t) {
    const int pA = t & 1;
    stage1(a.Hst + HO1 + (size_t)(pA ^ 1) * HBUF, 1024);
    __syncthreads();
    if (isL0) {  // D0 gate MFMAs (h0(t-1) already in plane 0)
      f32x4 acc = {0.f, 0.f, 0.f, 0.f};
      const char* arow = HC + bb * HROW;
      for (int kb = 0; kb < 16; ++kb)
        acc = mfma16(*(const f16x8*)(arow + ((lq * 16 + kb * 64) ^ aswz)),
                     *(const f16x8*)(wD + (size_t)kb * 512), acc);
      #pragma unroll
      for (int j = 0; j < 4; ++j) TTw[bb * 18 + lq * 4 + j] = acc[j];
    } else if (wid == 4) {
      fcwave(t, true);
    }
    __syncthreads();
    if (isL0) {  // c0 update with x -> h0(t)
      float ac[4];
      #pragma unroll
      for (int q = 0; q < 4; ++q)
        ac[q] = TTw[(4 * uu + q) * 18 + bb] + bL[128 + q * 16 + unitL];
      #pragma unroll
      for (int q = 0; q < 4; ++q)
        #pragma unroll
        for (int k = 0; k < 8; ++k)
          ac[q] = fmaf(x_lds[bb * 9 + k], WxL[576 + (q * 16 + unitL) * 9 + k], ac[q]);
      c01 = sigm(ac[1]) * c01 + sigm(ac[0]) * tanh_f(ac[2]);
      float h = sigm(ac[3]) * tanh_f(c01);
      unsigned short* hplane = a.Hst + HO0 + (size_t)(pA ^ 1) * HBUF;
      st2_cg((void*)(hplane + (size_t)rowG * 512 + 16 * s + unitL),
             (unsigned)__half_as_ushort(__float2half_rn(h)));
    }
    gbar();
    stage1(a.Hst + HO0 + (size_t)(pA ^ 1) * HBUF, 0);   // h0(t) -> plane 0
    __syncthreads();
    if (!isL0) {  // D1 gates + c1 update -> h1(t)
      f32x4 acc = {0.f, 0.f, 0.f, 0.f};
      const char* arow = HC + bb * HROW;
      for (int kb = 0; kb < 32; ++kb)
        acc = mfma16(*(const f16x8*)(arow + ((lq * 16 + kb * 64) ^ aswz)),
                     *(const f16x8*)(wD + (size_t)kb * 512), acc);
      #pragma unroll
      for (int j = 0; j < 4; ++j) TTw[bb * 18 + lq * 4 + j] = acc[j];
      float ac[4];
      #pragma unroll
      for (int q = 0; q < 4; ++q)
        ac[q] = TTw[(4 * uu + q) * 18 + bb] + bL[192 + q * 16 + unitL];
      c01 = sigm(ac[1]) * c01 + sigm(ac[0]) * tanh_f(ac[2]);
      float h = sigm(ac[3]) * tanh_f(c01);
      unsigned short* hplane = a.Hst + HO1 + (size_t)pA * HBUF;
      st2_cg((void*)(hplane + (size_t)rowG * 512 + 16 * s + unitL),
             (unsigned)__half_as_ushort(__float2half_rn(h)));
    }
    gbar();
  }

  // ================= epilogue: pred(95) from h1(95) in buf 1 =================
  stage1(a.Hst + HO1 + (size_t)1 * HBUF, 1024);
  __syncthreads();
  if (wid == 4 && s == 0) {
    const int pb_ = lane & 15, dd = (lane >> 4) & 1, hf = lane >> 5;
    const char* hp = HC + pb_ * HROW;
    const int fswz = (pb_ & 7) << 4;
    const float* wr = a.fcW + dd * 512 + hf * 256;
    float r = 0.f;
    #pragma unroll 8
    for (int j = 0; j < 32; ++j) {
      f16x8 v = *(const f16x8*)(hp + ((1024 + hf * 512 + j * 16) ^ fswz));
      float4 w0 = *(const float4*)(wr + j * 8);
      float4 w1 = *(const float4*)(wr + j * 8 + 4);
      r = fmaf((float)v[0], w0.x, r); r = fmaf((float)v[1], w0.y, r);
      r = fmaf((float)v[2], w0.z, r); r = fmaf((float)v[3], w0.w, r);
      r = fmaf((float)v[4], w1.x, r); r = fmaf((float)v[5], w1.y, r);
      r = fmaf((float)v[6], w1.z, r); r = fmaf((float)v[7], w1.w, r);
    }
    r += __shfl_xor(r, 32);
    if (lane < 32)
      a.out[(size_t)(16 * g + pb_) * (T_OUT * D_OUT) + (size_t)95 * D_OUT + dd] = r + pWb[24 + dd];
  }
}

extern "C" void kernel_launch(void* const* d_in, const int* in_sizes, int n_in,
                              void* d_out, int out_size, void* d_ws, size_t ws_size,
                              hipStream_t stream) {
  (void)in_sizes; (void)n_in; (void)out_size; (void)ws_size;
  const float* src   = (const float*)d_in[0];
  const float* eWih0 = (const float*)d_in[1];
  const float* eWhh0 = (const float*)d_in[2];
  const float* eb0   = (const float*)d_in[3];
  const float* eWih1 = (const float*)d_in[4];
  const float* eWhh1 = (const float*)d_in[5];
  const float* eb1   = (const float*)d_in[6];
  const float* dWih0 = (const float*)d_in[7];
  const float* dWhh0 = (const float*)d_in[8];
  const float* db0   = (const float*)d_in[9];
  const float* dWih1 = (const float*)d_in[10];
  const float* dWhh1 = (const float*)d_in[11];
  const float* db1   = (const float*)d_in[12];
  const float* fcW   = (const float*)d_in[13];
  const float* fcb   = (const float*)d_in[14];
  const float* pW    = (const float*)d_in[15];
  const float* pb    = (const float*)d_in[16];

  unsigned char* ws = (unsigned char*)d_ws;
  unsigned* cnt = (unsigned*)ws;                       // 4 KB slot barriers
  unsigned short* W = (unsigned short*)(ws + 4096);    // 12.6 MB fp16 tiled weights
  unsigned short* Hst = W + W_TOTAL;                   // 1 MB fp16 h-state

  (void)hipMemsetAsync(d_ws, 0, 4096, stream);
  (void)hipMemsetAsync((void*)Hst, 0, (size_t)4 * HBUF * sizeof(unsigned short), stream);

  hipLaunchKernelGGL(conv_kernel, dim3(W_TOTAL / 256), dim3(256), 0, stream,
                     eWhh0, eWih1, eWhh1, dWhh0, dWih1, dWhh1, W);

  Args a;
  a.src = src; a.eWih0 = eWih0; a.eb0 = eb0; a.eb1 = eb1;
  a.dWih0 = dWih0; a.db0 = db0; a.db1 = db1;
  a.fcW = fcW; a.fcb = fcb; a.pW = pW; a.pb = pb;
  a.W = W; a.Hst = Hst; a.out = (float*)d_out; a.cnt = cnt;

  // LDS: 32768 (HC) + (2304 + 32 + 144 + 1152 + 256 + 32)*4 = 48448 B
  const size_t smem_bytes = (size_t)ROWS * HROW + (2304 + 32 + 144 + 1152 + 256 + 32) * sizeof(float);
  hipLaunchKernelGGL(forecast_kernel, dim3(NGRP * WPG), dim3(NT), smem_bytes, stream, a);
}

// Round 12
// 4396.625 us; speedup vs baseline: 10.3634x; 1.1664x over previous
//
#include <hip/hip_runtime.h>
#include <hip/hip_fp16.h>
#include <math.h>

#define F 8
#define T_IN 336
#define T_OUT 96
#define D_OUT 2
#define NGRP 16      // batch groups (16 rows each); WG handles TWO groups
#define WPG 32       // workgroups per group (unit slices)
#define ROWS 16
#define NT 512
#define HROW 2048    // LDS hcat row stride bytes

// weight regions (shorts), kb-major tiled: [(s*4+w)][kb][lane(64)][8]
#define WE0 0
#define WE1 1048576
#define WD0 3145728
#define WD1 4194304
#define W_TOTAL 6291456
// h-state planes (shorts)
#define HO0 0
#define HO1 262144
#define HBUF 131072

using f32x4 = __attribute__((ext_vector_type(4))) float;
using f16x8 = __attribute__((ext_vector_type(8))) _Float16;

struct Args {
  const float *src;
  const float *eWih0, *eb0, *eb1;
  const float *dWih0, *db0, *db1;
  const float *fcW, *fcb, *pW, *pb;
  const unsigned short *W;
  unsigned short *Hst;
  float *out;
  unsigned *cnt;     // [NGRP][32] slot barrier
};

__device__ __forceinline__ float sigm(float x) { return 1.f / (1.f + __expf(-x)); }
__device__ __forceinline__ float tanh_f(float x) {
  float e = __expf(-2.f * fabsf(x));
  float r = (1.f - e) / (1.f + e);
  return copysignf(r, x);
}
__device__ __forceinline__ f32x4 mfma16(f16x8 a, f16x8 b, f32x4 c) {
  return __builtin_amdgcn_mfma_f32_16x16x32_f16(a, b, c, 0, 0, 0);
}
__device__ __forceinline__ void ld16_cg(uint4& d, const void* p) {
  asm volatile("global_load_dwordx4 %0, %1, off sc0 sc1" : "=v"(d) : "v"(p));
}
__device__ __forceinline__ void st2_cg(void* p, unsigned v) {
  asm volatile("global_store_short %0, %1, off sc0 sc1" :: "v"(p), "v"(v) : "memory");
}

// fp32 -> fp16, kb-major wave-fragment layout (identical to rounds 7-11)
__global__ __launch_bounds__(256) void conv_kernel(
    const float* eWhh0, const float* eWih1, const float* eWhh1,
    const float* dWhh0, const float* dWih1, const float* dWhh1,
    unsigned short* W) {
  size_t i = (size_t)blockIdx.x * 256 + threadIdx.x;
  if (i >= W_TOTAL) return;
  int set, j;
  if (i < WE1)      { set = 0; j = (int)i; }
  else if (i < WD0) { set = 1; j = (int)(i - WE1); }
  else if (i < WD1) { set = 2; j = (int)(i - WD0); }
  else              { set = 3; j = (int)(i - WD1); }
  const int big = (set == 1 || set == 3);
  const int e = j & 7, lane = (j >> 3) & 63, r = j >> 9;
  const int kb = big ? (r & 31) : (r & 15);
  const int sw = big ? (r >> 5) : (r >> 4);
  const int s = sw >> 2, w = sw & 3;
  const int c = lane & 15;
  const int n = (c & 3) * 512 + 16 * s + 4 * w + (c >> 2);
  const int k = kb * 32 + (lane >> 4) * 8 + e;
  float v;
  if (set == 0)      v = eWhh0[(size_t)n * 512 + k];
  else if (set == 1) v = (k < 512) ? eWih1[(size_t)n * 512 + k] : eWhh1[(size_t)n * 512 + k - 512];
  else if (set == 2) v = dWhh0[(size_t)n * 512 + k];
  else               v = (k < 512) ? dWih1[(size_t)n * 512 + k] : dWhh1[(size_t)n * 512 + k - 512];
  W[i] = __half_as_ushort(__float2half_rn(v));
}

__global__ __launch_bounds__(NT, 2) void forecast_kernel(Args a) {
  extern __shared__ char smem[];
  char* HCa = smem;                          // [16][2048B] group A hcat, XOR-swizzled
  char* HCb = smem + 32768;                  // group B hcat
  float* TT = (float*)(smem + 65536);        // [8 waves][16][18] per-wave scratch
  float* p_lds = TT + 8 * 288;               // [32]
  float* x_lds = p_lds + 32;                 // [16][9]
  float* WxL = x_lds + 144;                  // [2 sets][64 rows][9]
  float* bL = WxL + 1152;                    // [4 sets][4 gates][16 units]
  float* pWb = bL + 256;                     // pW[16], pb[8], fcb[2]

  const int tid = threadIdx.x;
  const int pr = blockIdx.x >> 5;       // pair id 0..7
  const int s = blockIdx.x & 31;        // unit slice
  const int gA = pr * 2, gB = pr * 2 + 1;
  const int lane = tid & 63, wid = tid >> 6;
  const int bb = lane & 15;
  const int lq = lane >> 4;
  const int isL0 = (wid < 4);
  const int w4 = isL0 ? wid : wid - 4;
  const int uu = lane >> 4;
  const int unitL = w4 * 4 + uu;
  float* TTw = TT + wid * 288;
  unsigned* slotA = a.cnt + gA * 32;
  unsigned* slotB = a.cnt + gB * 32;
  unsigned bsA = 0, bsB = 0;

  const int nkbE = isL0 ? 16 : 32;
  const unsigned short* wE = a.W + (isL0 ? WE0 : WE1) + (size_t)(s * 4 + w4) * nkbE * 512 + lane * 8;
  const unsigned short* wD = a.W + (isL0 ? WD0 : WD1) + (size_t)(s * 4 + w4) * nkbE * 512 + lane * 8;

  for (int e = tid; e < 1152; e += NT) {
    int set = e / 576, e2 = e % 576, row = e2 / 9, k = e2 % 9;
    const float* sw = set ? a.dWih0 : a.eWih0;
    WxL[e] = (k < 8) ? sw[(size_t)((row >> 4) * 512 + 16 * s + (row & 15)) * 8 + k] : 0.f;
  }
  if (tid < 256) {
    int bs = tid >> 6, q = (tid >> 4) & 3, u2 = tid & 15;
    const float* sp = bs == 0 ? a.eb0 : bs == 1 ? a.eb1 : bs == 2 ? a.db0 : a.db1;
    bL[tid] = sp[q * 512 + 16 * s + u2];
  }
  if (tid < 16) pWb[tid] = a.pW[tid];
  else if (tid < 24) pWb[tid] = a.pb[tid - 16];
  else if (tid < 26) pWb[tid] = a.fcb[tid - 24];
  __syncthreads();

  float cA = 0.f, cB = 0.f;   // per-group cell state (c0 on L0 waves, c1 on L1 waves)
  const int srow = tid >> 5, seg = tid & 31;
  const int wswz = (srow & 7) << 4;
  const int aswz = (bb & 7) << 4;

  // wait: wave0 polls group slots until all >= target, then release WG
  auto waitG = [&](unsigned* slots, unsigned target) {
    if (wid == 0) {
      long gd = 0;
      for (;;) {
        unsigned v = (lane < 32 && lane != s)
            ? __hip_atomic_load(slots + lane, __ATOMIC_RELAXED, __HIP_MEMORY_SCOPE_AGENT)
            : target;
        if (__all((int)(v >= target))) break;
        __builtin_amdgcn_s_sleep(1);
        if (++gd > (1L << 16)) break;   // fail-fast, never hang
      }
    }
    __syncthreads();
    asm volatile("" ::: "memory");
  };
  // arrive: drain sc stores, then publish stage count (no poll)
  auto arriveG = [&](unsigned* slots, unsigned target) {
    asm volatile("s_waitcnt vmcnt(0)" ::: "memory");
    __syncthreads();
    if (tid == 0)
      __hip_atomic_store(slots + s, target, __ATOMIC_RELAXED, __HIP_MEMORY_SCOPE_AGENT);
  };

  auto stage2 = [&](char* HC, const unsigned short* b0, const unsigned short* b1, int g) {
    const unsigned short* p0 = b0 + (size_t)(16 * g + srow) * 512 + seg * 8;
    const unsigned short* p1 = b1 + (size_t)(16 * g + srow) * 512 + seg * 8;
    uint4 q0, q1, q2, q3;
    ld16_cg(q0, p0); ld16_cg(q1, p0 + 256); ld16_cg(q2, p1); ld16_cg(q3, p1 + 256);
    asm volatile("s_waitcnt vmcnt(0)" ::: "memory");
    __builtin_amdgcn_sched_barrier(0);
    char* d = HC + srow * HROW + ((seg * 16) ^ wswz);
    *(uint4*)d = q0; *(uint4*)(d + 512) = q1;
    *(uint4*)(d + 1024) = q2; *(uint4*)(d + 1536) = q3;
  };
  auto stage1 = [&](char* HC, const unsigned short* b0, int plane, int g) {
    const unsigned short* p0 = b0 + (size_t)(16 * g + srow) * 512 + seg * 8;
    uint4 q0, q1;
    ld16_cg(q0, p0); ld16_cg(q1, p0 + 256);
    asm volatile("s_waitcnt vmcnt(0)" ::: "memory");
    __builtin_amdgcn_sched_barrier(0);
    char* d = HC + srow * HROW + plane + ((seg * 16) ^ wswz);
    *(uint4*)d = q0; *(uint4*)(d + 512) = q1;
  };
  auto fcw = [&](char* HC, int g, int t) {   // wave 4: pred + x for group's 16 rows
    const int pb_ = lane & 15, dd = (lane >> 4) & 1, hf = lane >> 5;
    const char* hp = HC + pb_ * HROW;
    const int fswz = (pb_ & 7) << 4;
    const float* wr = a.fcW + dd * 512 + hf * 256;
    float r = 0.f;
    #pragma unroll 8
    for (int j = 0; j < 32; ++j) {
      f16x8 v = *(const f16x8*)(hp + ((1024 + hf * 512 + j * 16) ^ fswz));
      float4 w0 = *(const float4*)(wr + j * 8);
      float4 w1 = *(const float4*)(wr + j * 8 + 4);
      r = fmaf((float)v[0], w0.x, r); r = fmaf((float)v[1], w0.y, r);
      r = fmaf((float)v[2], w0.z, r); r = fmaf((float)v[3], w0.w, r);
      r = fmaf((float)v[4], w1.x, r); r = fmaf((float)v[5], w1.y, r);
      r = fmaf((float)v[6], w1.z, r); r = fmaf((float)v[7], w1.w, r);
    }
    r += __shfl_xor(r, 32);
    if (lane < 32) {
      float pred = r + pWb[24 + dd];
      if (t == 0) pred = a.src[(size_t)(16 * g + pb_) * (T_IN * F) + 335 * F + dd * 2];
      p_lds[pb_ * 2 + dd] = pred;
      if (s == 0 && t > 0)
        a.out[(size_t)(16 * g + pb_) * (T_OUT * D_OUT) + (size_t)(t - 1) * D_OUT + dd] = pred;
    }
    const int bx = lane >> 2, j0 = (lane & 3) * 2;
    float pr0 = p_lds[bx * 2], pr1 = p_lds[bx * 2 + 1];
    x_lds[bx * 9 + j0]     = pWb[16 + j0]     + pr0 * pWb[j0 * 2]       + pr1 * pWb[j0 * 2 + 1];
    x_lds[bx * 9 + j0 + 1] = pWb[16 + j0 + 1] + pr0 * pWb[(j0 + 1) * 2] + pr1 * pWb[(j0 + 1) * 2 + 1];
  };

  // ---------------- encoder phase (one group) ----------------
  auto encPhase = [&](char* HC, unsigned* slots, unsigned& bs, float& c01, int g, int t) {
    waitG(slots, bs);
    const int buf = t & 1, nbuf = buf ^ 1;
    stage2(HC, a.Hst + HO0 + (size_t)buf * HBUF, a.Hst + HO1 + (size_t)buf * HBUF, g);
    __syncthreads();
    const bool active = isL0 ? (t < T_IN) : (t >= 1);
    if (active) {
      f32x4 acc = {0.f, 0.f, 0.f, 0.f};
      const char* arow = HC + bb * HROW;
      for (int kb = 0; kb < nkbE; ++kb)
        acc = mfma16(*(const f16x8*)(arow + ((lq * 16 + kb * 64) ^ aswz)),
                     *(const f16x8*)(wE + (size_t)kb * 512), acc);
      #pragma unroll
      for (int j = 0; j < 4; ++j) TTw[bb * 18 + lq * 4 + j] = acc[j];
      float ac[4];
      #pragma unroll
      for (int q = 0; q < 4; ++q)
        ac[q] = TTw[(4 * uu + q) * 18 + bb] + bL[(isL0 ? 0 : 64) + q * 16 + unitL];
      const int rowG = 16 * g + bb;
      if (isL0) {
        const float* xr = a.src + (size_t)rowG * (T_IN * F) + t * F;
        float4 x0 = *(const float4*)xr, x1 = *(const float4*)(xr + 4);
        float xv[8] = {x0.x, x0.y, x0.z, x0.w, x1.x, x1.y, x1.z, x1.w};
        #pragma unroll
        for (int q = 0; q < 4; ++q)
          #pragma unroll
          for (int k = 0; k < 8; ++k)
            ac[q] = fmaf(xv[k], WxL[(q * 16 + unitL) * 9 + k], ac[q]);
      }
      c01 = sigm(ac[1]) * c01 + sigm(ac[0]) * tanh_f(ac[2]);
      float h = sigm(ac[3]) * tanh_f(c01);
      unsigned short* hplane = a.Hst + (isL0 ? HO0 : HO1) + (size_t)nbuf * HBUF;
      st2_cg((void*)(hplane + (size_t)rowG * 512 + 16 * s + unitL),
             (unsigned)__half_as_ushort(__float2half_rn(h)));
    }
    arriveG(slots, ++bs);
  };

  // ---------------- decoder phase 1 (h0 + fc/proj) ----------------
  auto decP1 = [&](char* HC, unsigned* slots, unsigned& bs, float& c01, int g, int t) {
    waitG(slots, bs);
    const int pA = t & 1;
    stage1(HC, a.Hst + HO1 + (size_t)(pA ^ 1) * HBUF, 1024, g);   // h1(t-1)
    __syncthreads();
    if (isL0) {   // D0 gates from plane 0 (h0(t-1), invariant)
      f32x4 acc = {0.f, 0.f, 0.f, 0.f};
      const char* arow = HC + bb * HROW;
      for (int kb = 0; kb < 16; ++kb)
        acc = mfma16(*(const f16x8*)(arow + ((lq * 16 + kb * 64) ^ aswz)),
                     *(const f16x8*)(wD + (size_t)kb * 512), acc);
      #pragma unroll
      for (int j = 0; j < 4; ++j) TTw[bb * 18 + lq * 4 + j] = acc[j];
    } else if (wid == 4) {
      fcw(HC, g, t);
    }
    __syncthreads();
    if (isL0) {   // c0 update with x -> h0(t)
      float ac[4];
      #pragma unroll
      for (int q = 0; q < 4; ++q)
        ac[q] = TTw[(4 * uu + q) * 18 + bb] + bL[128 + q * 16 + unitL];
      #pragma unroll
      for (int q = 0; q < 4; ++q)
        #pragma unroll
        for (int k = 0; k < 8; ++k)
          ac[q] = fmaf(x_lds[bb * 9 + k], WxL[576 + (q * 16 + unitL) * 9 + k], ac[q]);
      c01 = sigm(ac[1]) * c01 + sigm(ac[0]) * tanh_f(ac[2]);
      float h = sigm(ac[3]) * tanh_f(c01);
      unsigned short* hplane = a.Hst + HO0 + (size_t)(pA ^ 1) * HBUF;
      st2_cg((void*)(hplane + (size_t)(16 * g + bb) * 512 + 16 * s + unitL),
             (unsigned)__half_as_ushort(__float2half_rn(h)));
    }
    arriveG(slots, ++bs);
  };

  // ---------------- decoder phase 2 (h1) ----------------
  auto decP2 = [&](char* HC, unsigned* slots, unsigned& bs, float& c01, int g, int t) {
    waitG(slots, bs);
    const int pA = t & 1;
    stage1(HC, a.Hst + HO0 + (size_t)(pA ^ 1) * HBUF, 0, g);   // h0(t) -> plane 0
    __syncthreads();
    if (!isL0) {
      f32x4 acc = {0.f, 0.f, 0.f, 0.f};
      const char* arow = HC + bb * HROW;
      for (int kb = 0; kb < 32; ++kb)
        acc = mfma16(*(const f16x8*)(arow + ((lq * 16 + kb * 64) ^ aswz)),
                     *(const f16x8*)(wD + (size_t)kb * 512), acc);
      #pragma unroll
      for (int j = 0; j < 4; ++j) TTw[bb * 18 + lq * 4 + j] = acc[j];
      float ac[4];
      #pragma unroll
      for (int q = 0; q < 4; ++q)
        ac[q] = TTw[(4 * uu + q) * 18 + bb] + bL[192 + q * 16 + unitL];
      c01 = sigm(ac[1]) * c01 + sigm(ac[0]) * tanh_f(ac[2]);
      float h = sigm(ac[3]) * tanh_f(c01);
      unsigned short* hplane = a.Hst + HO1 + (size_t)pA * HBUF;
      st2_cg((void*)(hplane + (size_t)(16 * g + bb) * 512 + 16 * s + unitL),
             (unsigned)__half_as_ushort(__float2half_rn(h)));
    }
    arriveG(slots, ++bs);
  };

  // ---------------- epilogue (pred 95) ----------------
  auto epi = [&](char* HC, unsigned* slots, unsigned& bs, int g) {
    waitG(slots, bs);
    stage1(HC, a.Hst + HO1 + (size_t)1 * HBUF, 1024, g);
    __syncthreads();
    if (wid == 4 && s == 0) {
      const int pb_ = lane & 15, dd = (lane >> 4) & 1, hf = lane >> 5;
      const char* hp = HC + pb_ * HROW;
      const int fswz = (pb_ & 7) << 4;
      const float* wr = a.fcW + dd * 512 + hf * 256;
      float r = 0.f;
      #pragma unroll 8
      for (int j = 0; j < 32; ++j) {
        f16x8 v = *(const f16x8*)(hp + ((1024 + hf * 512 + j * 16) ^ fswz));
        float4 w0 = *(const float4*)(wr + j * 8);
        float4 w1 = *(const float4*)(wr + j * 8 + 4);
        r = fmaf((float)v[0], w0.x, r); r = fmaf((float)v[1], w0.y, r);
        r = fmaf((float)v[2], w0.z, r); r = fmaf((float)v[3], w0.w, r);
        r = fmaf((float)v[4], w1.x, r); r = fmaf((float)v[5], w1.y, r);
        r = fmaf((float)v[6], w1.z, r); r = fmaf((float)v[7], w1.w, r);
      }
      r += __shfl_xor(r, 32);
      if (lane < 32)
        a.out[(size_t)(16 * g + pb_) * (T_OUT * D_OUT) + (size_t)95 * D_OUT + dd] = r + pWb[24 + dd];
    }
    __syncthreads();
  };

  // ================= main: interleaved dual-group =================
  for (int t = 0; t <= T_IN; ++t) {
    encPhase(HCa, slotA, bsA, cA, gA, t);
    encPhase(HCb, slotB, bsB, cB, gB, t);
  }
  for (int t = 0; t < T_OUT; ++t) {
    decP1(HCa, slotA, bsA, cA, gA, t);
    decP1(HCb, slotB, bsB, cB, gB, t);
    decP2(HCa, slotA, bsA, cA, gA, t);
    decP2(HCb, slotB, bsB, cB, gB, t);
  }
  epi(HCa, slotA, bsA, gA);
  epi(HCb, slotB, bsB, gB);
}

extern "C" void kernel_launch(void* const* d_in, const int* in_sizes, int n_in,
                              void* d_out, int out_size, void* d_ws, size_t ws_size,
                              hipStream_t stream) {
  (void)in_sizes; (void)n_in; (void)out_size; (void)ws_size;
  const float* src   = (const float*)d_in[0];
  const float* eWih0 = (const float*)d_in[1];
  const float* eWhh0 = (const float*)d_in[2];
  const float* eb0   = (const float*)d_in[3];
  const float* eWih1 = (const float*)d_in[4];
  const float* eWhh1 = (const float*)d_in[5];
  const float* eb1   = (const float*)d_in[6];
  const float* dWih0 = (const float*)d_in[7];
  const float* dWhh0 = (const float*)d_in[8];
  const float* db0   = (const float*)d_in[9];
  const float* dWih1 = (const float*)d_in[10];
  const float* dWhh1 = (const float*)d_in[11];
  const float* db1   = (const float*)d_in[12];
  const float* fcW   = (const float*)d_in[13];
  const float* fcb   = (const float*)d_in[14];
  const float* pW    = (const float*)d_in[15];
  const float* pb    = (const float*)d_in[16];

  unsigned char* ws = (unsigned char*)d_ws;
  unsigned* cnt = (unsigned*)ws;                       // 4 KB slot barriers
  unsigned short* W = (unsigned short*)(ws + 4096);    // 12.6 MB fp16 tiled weights
  unsigned short* Hst = W + W_TOTAL;                   // 1 MB fp16 h-state

  (void)hipMemsetAsync(d_ws, 0, 4096, stream);
  (void)hipMemsetAsync((void*)Hst, 0, (size_t)4 * HBUF * sizeof(unsigned short), stream);

  hipLaunchKernelGGL(conv_kernel, dim3(W_TOTAL / 256), dim3(256), 0, stream,
                     eWhh0, eWih1, eWhh1, dWhh0, dWih1, dWhh1, W);

  Args a;
  a.src = src; a.eWih0 = eWih0; a.eb0 = eb0; a.eb1 = eb1;
  a.dWih0 = dWih0; a.db0 = db0; a.db1 = db1;
  a.fcW = fcW; a.fcb = fcb; a.pW = pW; a.pb = pb;
  a.W = W; a.Hst = Hst; a.out = (float*)d_out; a.cnt = cnt;

  // LDS: 65536 (HCa+HCb) + (2304 + 32 + 144 + 1152 + 256 + 32)*4 = 81216 B
  const size_t smem_bytes = 65536 + (2304 + 32 + 144 + 1152 + 256 + 32) * sizeof(float);
  hipLaunchKernelGGL(forecast_kernel, dim3((NGRP / 2) * WPG), dim3(NT), smem_bytes, stream, a);
}

// Round 13
// 3415.564 us; speedup vs baseline: 13.3401x; 1.2872x over previous
//
#include <hip/hip_runtime.h>
#include <hip/hip_fp16.h>
#include <math.h>

#define F 8
#define T_IN 336
#define T_OUT 96
#define D_OUT 2
#define NGRP 16      // batch groups (16 rows each); WG handles TWO groups
#define WPG 32       // workgroups per group (unit slices)
#define ROWS 16
#define NT 512
#define HROW 2048    // LDS hcat row stride bytes

// weight regions (shorts), kb-major tiled: [(s*4+w)][kb][lane(64)][8]
#define WE0 0
#define WE1 1048576
#define WD0 3145728
#define WD1 4194304
#define W_TOTAL 6291456
// h-state planes (shorts)
#define HO0 0
#define HO1 262144
#define HBUF 131072

using f32x4 = __attribute__((ext_vector_type(4))) float;
using f16x8 = __attribute__((ext_vector_type(8))) _Float16;

struct Args {
  const float *src;
  const float *eWih0, *eb0, *eb1;
  const float *dWih0, *db0, *db1;
  const float *fcW, *fcb, *pW, *pb;
  const unsigned short *W;
  unsigned short *Hst;
  float *out;
  unsigned *cnt;     // [NGRP][32] slot barrier
};

__device__ __forceinline__ float sigm(float x) { return 1.f / (1.f + __expf(-x)); }
__device__ __forceinline__ float tanh_f(float x) {
  float e = __expf(-2.f * fabsf(x));
  float r = (1.f - e) / (1.f + e);
  return copysignf(r, x);
}
__device__ __forceinline__ f32x4 mfma16(f16x8 a, f16x8 b, f32x4 c) {
  return __builtin_amdgcn_mfma_f32_16x16x32_f16(a, b, c, 0, 0, 0);
}
__device__ __forceinline__ void ld16_cg(uint4& d, const void* p) {
  asm volatile("global_load_dwordx4 %0, %1, off sc0 sc1" : "=v"(d) : "v"(p));
}
__device__ __forceinline__ void st2_cg(void* p, unsigned v) {
  asm volatile("global_store_short %0, %1, off sc0 sc1" :: "v"(p), "v"(v) : "memory");
}

// fp32 -> fp16, kb-major wave-fragment layout (identical to rounds 7-12)
__global__ __launch_bounds__(256) void conv_kernel(
    const float* eWhh0, const float* eWih1, const float* eWhh1,
    const float* dWhh0, const float* dWih1, const float* dWhh1,
    unsigned short* W) {
  size_t i = (size_t)blockIdx.x * 256 + threadIdx.x;
  if (i >= W_TOTAL) return;
  int set, j;
  if (i < WE1)      { set = 0; j = (int)i; }
  else if (i < WD0) { set = 1; j = (int)(i - WE1); }
  else if (i < WD1) { set = 2; j = (int)(i - WD0); }
  else              { set = 3; j = (int)(i - WD1); }
  const int big = (set == 1 || set == 3);
  const int e = j & 7, lane = (j >> 3) & 63, r = j >> 9;
  const int kb = big ? (r & 31) : (r & 15);
  const int sw = big ? (r >> 5) : (r >> 4);
  const int s = sw >> 2, w = sw & 3;
  const int c = lane & 15;
  const int n = (c & 3) * 512 + 16 * s + 4 * w + (c >> 2);
  const int k = kb * 32 + (lane >> 4) * 8 + e;
  float v;
  if (set == 0)      v = eWhh0[(size_t)n * 512 + k];
  else if (set == 1) v = (k < 512) ? eWih1[(size_t)n * 512 + k] : eWhh1[(size_t)n * 512 + k - 512];
  else if (set == 2) v = dWhh0[(size_t)n * 512 + k];
  else               v = (k < 512) ? dWih1[(size_t)n * 512 + k] : dWhh1[(size_t)n * 512 + k - 512];
  W[i] = __half_as_ushort(__float2half_rn(v));
}

__global__ __launch_bounds__(NT, 2) void forecast_kernel(Args a) {
  extern __shared__ char smem[];
  char* HCa = smem;                          // [16][2048B] group A hcat, XOR-swizzled
  char* HCb = smem + 32768;                  // group B hcat
  float* TT = (float*)(smem + 65536);        // [8 waves][16][18] per-wave scratch
  float* p_lds = TT + 8 * 288;               // [32]
  float* x_lds = p_lds + 32;                 // [16][9]
  float* WxL = x_lds + 144;                  // [2 sets][64 rows][9]
  float* bL = WxL + 1152;                    // [4 sets][4 gates][16 units]
  float* pWb = bL + 256;                     // pW[16], pb[8], fcb[2]

  const int tid = threadIdx.x;
  const int pr = blockIdx.x >> 5;       // pair id 0..7
  const int s = blockIdx.x & 31;        // unit slice
  const int gA = pr * 2, gB = pr * 2 + 1;
  const int lane = tid & 63, wid = tid >> 6;
  const int bb = lane & 15;
  const int lq = lane >> 4;
  const int isL0 = (wid < 4);
  const int w4 = isL0 ? wid : wid - 4;
  const int uu = lane >> 4;
  const int unitL = w4 * 4 + uu;
  float* TTw = TT + wid * 288;
  unsigned* slotA = a.cnt + gA * 32;
  unsigned* slotB = a.cnt + gB * 32;
  unsigned bsA = 0, bsB = 0;

  const int nkbE = isL0 ? 16 : 32;
  const unsigned short* wE = a.W + (isL0 ? WE0 : WE1) + (size_t)(s * 4 + w4) * nkbE * 512 + lane * 8;
  const unsigned short* wD = a.W + (isL0 ? WD0 : WD1) + (size_t)(s * 4 + w4) * nkbE * 512 + lane * 8;

  // ---- weight registers: whole per-wave weight set lives in VGPRs ----
  f16x8 wreg[32];
  auto loadW = [&](const unsigned short* wp) {
    #pragma unroll
    for (int kb = 0; kb < 32; ++kb)
      if (kb < nkbE) wreg[kb] = *(const f16x8*)(wp + (size_t)kb * 512);
  };
  loadW(wE);

  for (int e = tid; e < 1152; e += NT) {
    int set = e / 576, e2 = e % 576, row = e2 / 9, k = e2 % 9;
    const float* sw = set ? a.dWih0 : a.eWih0;
    WxL[e] = (k < 8) ? sw[(size_t)((row >> 4) * 512 + 16 * s + (row & 15)) * 8 + k] : 0.f;
  }
  if (tid < 256) {
    int bs = tid >> 6, q = (tid >> 4) & 3, u2 = tid & 15;
    const float* sp = bs == 0 ? a.eb0 : bs == 1 ? a.eb1 : bs == 2 ? a.db0 : a.db1;
    bL[tid] = sp[q * 512 + 16 * s + u2];
  }
  if (tid < 16) pWb[tid] = a.pW[tid];
  else if (tid < 24) pWb[tid] = a.pb[tid - 16];
  else if (tid < 26) pWb[tid] = a.fcb[tid - 24];
  __syncthreads();

  float cA = 0.f, cB = 0.f;   // per-group cell state (c0 on L0 waves, c1 on L1 waves)
  const int srow = tid >> 5, seg = tid & 31;
  const int wswz = (srow & 7) << 4;
  const int aswz = (bb & 7) << 4;

  // wait: wave0 polls group slots until all >= target, then release WG
  auto waitG = [&](unsigned* slots, unsigned target) {
    if (wid == 0) {
      long gd = 0;
      for (;;) {
        unsigned v = (lane < 32 && lane != s)
            ? __hip_atomic_load(slots + lane, __ATOMIC_RELAXED, __HIP_MEMORY_SCOPE_AGENT)
            : target;
        if (__all((int)(v >= target))) break;
        __builtin_amdgcn_s_sleep(1);
        if (++gd > (1L << 16)) break;   // fail-fast, never hang
      }
    }
    __syncthreads();
    asm volatile("" ::: "memory");
  };
  // arrive: drain sc stores, then publish stage count (no poll)
  auto arriveG = [&](unsigned* slots, unsigned target) {
    asm volatile("s_waitcnt vmcnt(0)" ::: "memory");
    __syncthreads();
    if (tid == 0)
      __hip_atomic_store(slots + s, target, __ATOMIC_RELAXED, __HIP_MEMORY_SCOPE_AGENT);
  };

  auto stage2 = [&](char* HC, const unsigned short* b0, const unsigned short* b1, int g) {
    const unsigned short* p0 = b0 + (size_t)(16 * g + srow) * 512 + seg * 8;
    const unsigned short* p1 = b1 + (size_t)(16 * g + srow) * 512 + seg * 8;
    uint4 q0, q1, q2, q3;
    ld16_cg(q0, p0); ld16_cg(q1, p0 + 256); ld16_cg(q2, p1); ld16_cg(q3, p1 + 256);
    asm volatile("s_waitcnt vmcnt(0)" ::: "memory");
    __builtin_amdgcn_sched_barrier(0);
    char* d = HC + srow * HROW + ((seg * 16) ^ wswz);
    *(uint4*)d = q0; *(uint4*)(d + 512) = q1;
    *(uint4*)(d + 1024) = q2; *(uint4*)(d + 1536) = q3;
  };
  auto stage1 = [&](char* HC, const unsigned short* b0, int plane, int g) {
    const unsigned short* p0 = b0 + (size_t)(16 * g + srow) * 512 + seg * 8;
    uint4 q0, q1;
    ld16_cg(q0, p0); ld16_cg(q1, p0 + 256);
    asm volatile("s_waitcnt vmcnt(0)" ::: "memory");
    __builtin_amdgcn_sched_barrier(0);
    char* d = HC + srow * HROW + plane + ((seg * 16) ^ wswz);
    *(uint4*)d = q0; *(uint4*)(d + 512) = q1;
  };
  auto fcw = [&](char* HC, int g, int t) {   // wave 4: pred + x for group's 16 rows
    const int pb_ = lane & 15, dd = (lane >> 4) & 1, hf = lane >> 5;
    const char* hp = HC + pb_ * HROW;
    const int fswz = (pb_ & 7) << 4;
    const float* wr = a.fcW + dd * 512 + hf * 256;
    float r = 0.f;
    #pragma unroll 8
    for (int j = 0; j < 32; ++j) {
      f16x8 v = *(const f16x8*)(hp + ((1024 + hf * 512 + j * 16) ^ fswz));
      float4 w0 = *(const float4*)(wr + j * 8);
      float4 w1 = *(const float4*)(wr + j * 8 + 4);
      r = fmaf((float)v[0], w0.x, r); r = fmaf((float)v[1], w0.y, r);
      r = fmaf((float)v[2], w0.z, r); r = fmaf((float)v[3], w0.w, r);
      r = fmaf((float)v[4], w1.x, r); r = fmaf((float)v[5], w1.y, r);
      r = fmaf((float)v[6], w1.z, r); r = fmaf((float)v[7], w1.w, r);
    }
    r += __shfl_xor(r, 32);
    if (lane < 32) {
      float pred = r + pWb[24 + dd];
      if (t == 0) pred = a.src[(size_t)(16 * g + pb_) * (T_IN * F) + 335 * F + dd * 2];
      p_lds[pb_ * 2 + dd] = pred;
      if (s == 0 && t > 0)
        a.out[(size_t)(16 * g + pb_) * (T_OUT * D_OUT) + (size_t)(t - 1) * D_OUT + dd] = pred;
    }
    const int bx = lane >> 2, j0 = (lane & 3) * 2;
    float pr0 = p_lds[bx * 2], pr1 = p_lds[bx * 2 + 1];
    x_lds[bx * 9 + j0]     = pWb[16 + j0]     + pr0 * pWb[j0 * 2]       + pr1 * pWb[j0 * 2 + 1];
    x_lds[bx * 9 + j0 + 1] = pWb[16 + j0 + 1] + pr0 * pWb[(j0 + 1) * 2] + pr1 * pWb[(j0 + 1) * 2 + 1];
  };

  // ---------------- encoder phase (one group) ----------------
  auto encPhase = [&](char* HC, unsigned* slots, unsigned& bs, float& c01, int g, int t) {
    waitG(slots, bs);
    const int buf = t & 1, nbuf = buf ^ 1;
    stage2(HC, a.Hst + HO0 + (size_t)buf * HBUF, a.Hst + HO1 + (size_t)buf * HBUF, g);
    __syncthreads();
    const bool active = isL0 ? (t < T_IN) : (t >= 1);
    if (active) {
      f32x4 acc = {0.f, 0.f, 0.f, 0.f};
      const char* arow = HC + bb * HROW;
      #pragma unroll
      for (int kb = 0; kb < 32; ++kb)
        if (kb < nkbE)
          acc = mfma16(*(const f16x8*)(arow + ((lq * 16 + kb * 64) ^ aswz)), wreg[kb], acc);
      #pragma unroll
      for (int j = 0; j < 4; ++j) TTw[bb * 18 + lq * 4 + j] = acc[j];
      float ac[4];
      #pragma unroll
      for (int q = 0; q < 4; ++q)
        ac[q] = TTw[(4 * uu + q) * 18 + bb] + bL[(isL0 ? 0 : 64) + q * 16 + unitL];
      const int rowG = 16 * g + bb;
      if (isL0) {
        const float* xr = a.src + (size_t)rowG * (T_IN * F) + t * F;
        float4 x0 = *(const float4*)xr, x1 = *(const float4*)(xr + 4);
        float xv[8] = {x0.x, x0.y, x0.z, x0.w, x1.x, x1.y, x1.z, x1.w};
        #pragma unroll
        for (int q = 0; q < 4; ++q)
          #pragma unroll
          for (int k = 0; k < 8; ++k)
            ac[q] = fmaf(xv[k], WxL[(q * 16 + unitL) * 9 + k], ac[q]);
      }
      c01 = sigm(ac[1]) * c01 + sigm(ac[0]) * tanh_f(ac[2]);
      float h = sigm(ac[3]) * tanh_f(c01);
      unsigned short* hplane = a.Hst + (isL0 ? HO0 : HO1) + (size_t)nbuf * HBUF;
      st2_cg((void*)(hplane + (size_t)rowG * 512 + 16 * s + unitL),
             (unsigned)__half_as_ushort(__float2half_rn(h)));
    }
    arriveG(slots, ++bs);
  };

  // ---------------- decoder phase 1 (h0 + fc/proj) ----------------
  auto decP1 = [&](char* HC, unsigned* slots, unsigned& bs, float& c01, int g, int t) {
    waitG(slots, bs);
    const int pA = t & 1;
    stage1(HC, a.Hst + HO1 + (size_t)(pA ^ 1) * HBUF, 1024, g);   // h1(t-1)
    __syncthreads();
    if (isL0) {   // D0 gates from plane 0 (h0(t-1), invariant)
      f32x4 acc = {0.f, 0.f, 0.f, 0.f};
      const char* arow = HC + bb * HROW;
      #pragma unroll
      for (int kb = 0; kb < 16; ++kb)
        acc = mfma16(*(const f16x8*)(arow + ((lq * 16 + kb * 64) ^ aswz)), wreg[kb], acc);
      #pragma unroll
      for (int j = 0; j < 4; ++j) TTw[bb * 18 + lq * 4 + j] = acc[j];
    } else if (wid == 4) {
      fcw(HC, g, t);
    }
    __syncthreads();
    if (isL0) {   // c0 update with x -> h0(t)
      float ac[4];
      #pragma unroll
      for (int q = 0; q < 4; ++q)
        ac[q] = TTw[(4 * uu + q) * 18 + bb] + bL[128 + q * 16 + unitL];
      #pragma unroll
      for (int q = 0; q < 4; ++q)
        #pragma unroll
        for (int k = 0; k < 8; ++k)
          ac[q] = fmaf(x_lds[bb * 9 + k], WxL[576 + (q * 16 + unitL) * 9 + k], ac[q]);
      c01 = sigm(ac[1]) * c01 + sigm(ac[0]) * tanh_f(ac[2]);
      float h = sigm(ac[3]) * tanh_f(c01);
      unsigned short* hplane = a.Hst + HO0 + (size_t)(pA ^ 1) * HBUF;
      st2_cg((void*)(hplane + (size_t)(16 * g + bb) * 512 + 16 * s + unitL),
             (unsigned)__half_as_ushort(__float2half_rn(h)));
    }
    arriveG(slots, ++bs);
  };

  // ---------------- decoder phase 2 (h1) ----------------
  auto decP2 = [&](char* HC, unsigned* slots, unsigned& bs, float& c01, int g, int t) {
    waitG(slots, bs);
    const int pA = t & 1;
    stage1(HC, a.Hst + HO0 + (size_t)(pA ^ 1) * HBUF, 0, g);   // h0(t) -> plane 0
    __syncthreads();
    if (!isL0) {
      f32x4 acc = {0.f, 0.f, 0.f, 0.f};
      const char* arow = HC + bb * HROW;
      #pragma unroll
      for (int kb = 0; kb < 32; ++kb)
        acc = mfma16(*(const f16x8*)(arow + ((lq * 16 + kb * 64) ^ aswz)), wreg[kb], acc);
      #pragma unroll
      for (int j = 0; j < 4; ++j) TTw[bb * 18 + lq * 4 + j] = acc[j];
      float ac[4];
      #pragma unroll
      for (int q = 0; q < 4; ++q)
        ac[q] = TTw[(4 * uu + q) * 18 + bb] + bL[192 + q * 16 + unitL];
      c01 = sigm(ac[1]) * c01 + sigm(ac[0]) * tanh_f(ac[2]);
      float h = sigm(ac[3]) * tanh_f(c01);
      unsigned short* hplane = a.Hst + HO1 + (size_t)pA * HBUF;
      st2_cg((void*)(hplane + (size_t)(16 * g + bb) * 512 + 16 * s + unitL),
             (unsigned)__half_as_ushort(__float2half_rn(h)));
    }
    arriveG(slots, ++bs);
  };

  // ---------------- epilogue (pred 95) ----------------
  auto epi = [&](char* HC, unsigned* slots, unsigned& bs, int g) {
    waitG(slots, bs);
    stage1(HC, a.Hst + HO1 + (size_t)1 * HBUF, 1024, g);
    __syncthreads();
    if (wid == 4 && s == 0) {
      const int pb_ = lane & 15, dd = (lane >> 4) & 1, hf = lane >> 5;
      const char* hp = HC + pb_ * HROW;
      const int fswz = (pb_ & 7) << 4;
      const float* wr = a.fcW + dd * 512 + hf * 256;
      float r = 0.f;
      #pragma unroll 8
      for (int j = 0; j < 32; ++j) {
        f16x8 v = *(const f16x8*)(hp + ((1024 + hf * 512 + j * 16) ^ fswz));
        float4 w0 = *(const float4*)(wr + j * 8);
        float4 w1 = *(const float4*)(wr + j * 8 + 4);
        r = fmaf((float)v[0], w0.x, r); r = fmaf((float)v[1], w0.y, r);
        r = fmaf((float)v[2], w0.z, r); r = fmaf((float)v[3], w0.w, r);
        r = fmaf((float)v[4], w1.x, r); r = fmaf((float)v[5], w1.y, r);
        r = fmaf((float)v[6], w1.z, r); r = fmaf((float)v[7], w1.w, r);
      }
      r += __shfl_xor(r, 32);
      if (lane < 32)
        a.out[(size_t)(16 * g + pb_) * (T_OUT * D_OUT) + (size_t)95 * D_OUT + dd] = r + pWb[24 + dd];
    }
    __syncthreads();
  };

  // ================= main: interleaved dual-group =================
  for (int t = 0; t <= T_IN; ++t) {
    encPhase(HCa, slotA, bsA, cA, gA, t);
    encPhase(HCb, slotB, bsB, cB, gB, t);
  }
  loadW(wD);   // swap weight registers: encoder -> decoder
  for (int t = 0; t < T_OUT; ++t) {
    decP1(HCa, slotA, bsA, cA, gA, t);
    decP1(HCb, slotB, bsB, cB, gB, t);
    decP2(HCa, slotA, bsA, cA, gA, t);
    decP2(HCb, slotB, bsB, cB, gB, t);
  }
  epi(HCa, slotA, bsA, gA);
  epi(HCb, slotB, bsB, gB);
}

extern "C" void kernel_launch(void* const* d_in, const int* in_sizes, int n_in,
                              void* d_out, int out_size, void* d_ws, size_t ws_size,
                              hipStream_t stream) {
  (void)in_sizes; (void)n_in; (void)out_size; (void)ws_size;
  const float* src   = (const float*)d_in[0];
  const float* eWih0 = (const float*)d_in[1];
  const float* eWhh0 = (const float*)d_in[2];
  const float* eb0   = (const float*)d_in[3];
  const float* eWih1 = (const float*)d_in[4];
  const float* eWhh1 = (const float*)d_in[5];
  const float* eb1   = (const float*)d_in[6];
  const float* dWih0 = (const float*)d_in[7];
  const float* dWhh0 = (const float*)d_in[8];
  const float* db0   = (const float*)d_in[9];
  const float* dWih1 = (const float*)d_in[10];
  const float* dWhh1 = (const float*)d_in[11];
  const float* db1   = (const float*)d_in[12];
  const float* fcW   = (const float*)d_in[13];
  const float* fcb   = (const float*)d_in[14];
  const float* pW    = (const float*)d_in[15];
  const float* pb    = (const float*)d_in[16];

  unsigned char* ws = (unsigned char*)d_ws;
  unsigned* cnt = (unsigned*)ws;                       // 4 KB slot barriers
  unsigned short* W = (unsigned short*)(ws + 4096);    // 12.6 MB fp16 tiled weights
  unsigned short* Hst = W + W_TOTAL;                   // 1 MB fp16 h-state

  (void)hipMemsetAsync(d_ws, 0, 4096, stream);
  (void)hipMemsetAsync((void*)Hst, 0, (size_t)4 * HBUF * sizeof(unsigned short), stream);

  hipLaunchKernelGGL(conv_kernel, dim3(W_TOTAL / 256), dim3(256), 0, stream,
                     eWhh0, eWih1, eWhh1, dWhh0, dWih1, dWhh1, W);

  Args a;
  a.src = src; a.eWih0 = eWih0; a.eb0 = eb0; a.eb1 = eb1;
  a.dWih0 = dWih0; a.db0 = db0; a.db1 = db1;
  a.fcW = fcW; a.fcb = fcb; a.pW = pW; a.pb = pb;
  a.W = W; a.Hst = Hst; a.out = (float*)d_out; a.cnt = cnt;

  // LDS: 65536 (HCa+HCb) + (2304 + 32 + 144 + 1152 + 256 + 32)*4 = 81216 B
  const size_t smem_bytes = 65536 + (2304 + 32 + 144 + 1152 + 256 + 32) * sizeof(float);
  hipLaunchKernelGGL(forecast_kernel, dim3((NGRP / 2) * WPG), dim3(NT), smem_bytes, stream, a);
}

// Round 14
// 3143.177 us; speedup vs baseline: 14.4962x; 1.0867x over previous
//
#include <hip/hip_runtime.h>
#include <hip/hip_fp16.h>
#include <math.h>

#define F 8
#define T_IN 336
#define T_OUT 96
#define D_OUT 2
#define NGRP 16
#define WPG 32
#define ROWS 16
#define NT 512
#define HROW 2048

#define WE0 0
#define WE1 1048576
#define WD0 3145728
#define WD1 4194304
#define W_TOTAL 6291456
#define HO0 0
#define HO1 262144
#define HBUF 131072

using f32x4 = __attribute__((ext_vector_type(4))) float;
using f16x8 = __attribute__((ext_vector_type(8))) _Float16;

struct Args {
  const float *src;
  const float *eWih0, *eb0, *eb1;
  const float *dWih0, *db0, *db1;
  const float *fcW, *fcb, *pW, *pb;
  const unsigned short *W;
  unsigned short *Hst;
  float *out;
  unsigned *cnt;
};

__device__ __forceinline__ float sigm(float x) { return 1.f / (1.f + __expf(-x)); }
__device__ __forceinline__ float tanh_f(float x) {
  float e = __expf(-2.f * fabsf(x));
  float r = (1.f - e) / (1.f + e);
  return copysignf(r, x);
}
__device__ __forceinline__ f32x4 mfma16(f16x8 a, f16x8 b, f32x4 c) {
  return __builtin_amdgcn_mfma_f32_16x16x32_f16(a, b, c, 0, 0, 0);
}
__device__ __forceinline__ void ld16_cg(uint4& d, const void* p) {
  asm volatile("global_load_dwordx4 %0, %1, off sc0 sc1" : "=v"(d) : "v"(p));
}
__device__ __forceinline__ void st2_cg(void* p, unsigned v) {
  asm volatile("global_store_short %0, %1, off sc0 sc1" :: "v"(p), "v"(v) : "memory");
}
__device__ __forceinline__ void vw0() { asm volatile("s_waitcnt vmcnt(0)" ::: "memory"); }
__device__ __forceinline__ void vw2() { asm volatile("s_waitcnt vmcnt(2)" ::: "memory"); }
__device__ __forceinline__ void vw4() { asm volatile("s_waitcnt vmcnt(4)" ::: "memory"); }

__global__ __launch_bounds__(256) void conv_kernel(
    const float* eWhh0, const float* eWih1, const float* eWhh1,
    const float* dWhh0, const float* dWih1, const float* dWhh1,
    unsigned short* W) {
  size_t i = (size_t)blockIdx.x * 256 + threadIdx.x;
  if (i >= W_TOTAL) return;
  int set, j;
  if (i < WE1)      { set = 0; j = (int)i; }
  else if (i < WD0) { set = 1; j = (int)(i - WE1); }
  else if (i < WD1) { set = 2; j = (int)(i - WD0); }
  else              { set = 3; j = (int)(i - WD1); }
  const int big = (set == 1 || set == 3);
  const int e = j & 7, lane = (j >> 3) & 63, r = j >> 9;
  const int kb = big ? (r & 31) : (r & 15);
  const int sw = big ? (r >> 5) : (r >> 4);
  const int s = sw >> 2, w = sw & 3;
  const int c = lane & 15;
  const int n = (c & 3) * 512 + 16 * s + 4 * w + (c >> 2);
  const int k = kb * 32 + (lane >> 4) * 8 + e;
  float v;
  if (set == 0)      v = eWhh0[(size_t)n * 512 + k];
  else if (set == 1) v = (k < 512) ? eWih1[(size_t)n * 512 + k] : eWhh1[(size_t)n * 512 + k - 512];
  else if (set == 2) v = dWhh0[(size_t)n * 512 + k];
  else               v = (k < 512) ? dWih1[(size_t)n * 512 + k] : dWhh1[(size_t)n * 512 + k - 512];
  W[i] = __half_as_ushort(__float2half_rn(v));
}

__global__ __launch_bounds__(NT, 2) void forecast_kernel(Args a) {
  extern __shared__ char smem[];
  char* HCa = smem;
  char* HCb = smem + 32768;
  float* TT = (float*)(smem + 65536);
  float* p_lds = TT + 8 * 288;
  float* x_lds = p_lds + 32;
  float* WxL = x_lds + 144;
  float* bL = WxL + 1152;
  float* pWb = bL + 256;

  const int tid = threadIdx.x;
  const int pr = blockIdx.x >> 5;
  const int s = blockIdx.x & 31;
  const int gA = pr * 2, gB = pr * 2 + 1;
  const int lane = tid & 63, wid = tid >> 6;
  const int bb = lane & 15;
  const int lq = lane >> 4;
  const int isL0 = (wid < 4);
  const int w4 = isL0 ? wid : wid - 4;
  const int uu = lane >> 4;
  const int unitL = w4 * 4 + uu;
  float* TTw = TT + wid * 288;
  unsigned* slotA = a.cnt + gA * 32;
  unsigned* slotB = a.cnt + gB * 32;
  unsigned bsA = 0, bsB = 0;

  unsigned short* H0 = a.Hst + HO0;
  unsigned short* H1 = a.Hst + HO1;

  const int nkbE = isL0 ? 16 : 32;
  const unsigned short* wE = a.W + (isL0 ? WE0 : WE1) + (size_t)(s * 4 + w4) * nkbE * 512 + lane * 8;
  const unsigned short* wD = a.W + (isL0 ? WD0 : WD1) + (size_t)(s * 4 + w4) * nkbE * 512 + lane * 8;

  f16x8 wreg[32];
  auto loadW = [&](const unsigned short* wp) {
    #pragma unroll
    for (int kb = 0; kb < 32; ++kb)
      if (kb < nkbE) wreg[kb] = *(const f16x8*)(wp + (size_t)kb * 512);
  };
  loadW(wE);

  for (int e = tid; e < 1152; e += NT) {
    int set = e / 576, e2 = e % 576, row = e2 / 9, k = e2 % 9;
    const float* sw = set ? a.dWih0 : a.eWih0;
    WxL[e] = (k < 8) ? sw[(size_t)((row >> 4) * 512 + 16 * s + (row & 15)) * 8 + k] : 0.f;
  }
  if (tid < 256) {
    int bs = tid >> 6, q = (tid >> 4) & 3, u2 = tid & 15;
    const float* sp = bs == 0 ? a.eb0 : bs == 1 ? a.eb1 : bs == 2 ? a.db0 : a.db1;
    bL[tid] = sp[q * 512 + 16 * s + u2];
  }
  if (tid < 16) pWb[tid] = a.pW[tid];
  else if (tid < 24) pWb[tid] = a.pb[tid - 16];
  else if (tid < 26) pWb[tid] = a.fcb[tid - 24];
  __syncthreads();

  float cA = 0.f, cB = 0.f;
  const int srow = tid >> 5, seg = tid & 31;
  const int wswz = (srow & 7) << 4;
  const int aswz = (bb & 7) << 4;

  uint4 pf0, pf1, pf2, pf3;   // prefetch registers (live across phases)

  auto pollG = [&](unsigned* slots, unsigned target) {
    if (wid == 0) {
      long gd = 0;
      for (;;) {
        unsigned v = (lane < 32 && lane != s)
            ? __hip_atomic_load(slots + lane, __ATOMIC_RELAXED, __HIP_MEMORY_SCOPE_AGENT)
            : target;
        if (__all((int)(v >= target))) break;
        __builtin_amdgcn_s_sleep(1);
        if (++gd > (1L << 16)) break;
      }
    }
    __syncthreads();
    asm volatile("" ::: "memory");
  };
  auto pub = [&](unsigned* slots, unsigned target) {
    if (tid == 0)
      __hip_atomic_store(slots + s, target, __ATOMIC_RELAXED, __HIP_MEMORY_SCOPE_AGENT);
  };
  auto issue2 = [&](const unsigned short* b0, const unsigned short* b1, int g) {
    const unsigned short* p0 = b0 + (size_t)(16 * g + srow) * 512 + seg * 8;
    const unsigned short* p1 = b1 + (size_t)(16 * g + srow) * 512 + seg * 8;
    ld16_cg(pf0, p0); ld16_cg(pf1, p0 + 256); ld16_cg(pf2, p1); ld16_cg(pf3, p1 + 256);
  };
  auto issue1 = [&](const unsigned short* b0, int g) {
    const unsigned short* p0 = b0 + (size_t)(16 * g + srow) * 512 + seg * 8;
    ld16_cg(pf0, p0); ld16_cg(pf1, p0 + 256);
  };
  auto write2 = [&](char* HC) {
    vw0();
    __builtin_amdgcn_sched_barrier(0);
    char* d = HC + srow * HROW + ((seg * 16) ^ wswz);
    *(uint4*)d = pf0; *(uint4*)(d + 512) = pf1;
    *(uint4*)(d + 1024) = pf2; *(uint4*)(d + 1536) = pf3;
    __syncthreads();
  };
  auto write1 = [&](char* HC, int plane) {
    vw0();
    __builtin_amdgcn_sched_barrier(0);
    char* d = HC + srow * HROW + plane + ((seg * 16) ^ wswz);
    *(uint4*)d = pf0; *(uint4*)(d + 512) = pf1;
    __syncthreads();
  };

  auto encCompute = [&](char* HC, float& c01, int g, int t) {
    const int nbuf = (t & 1) ^ 1;
    const bool active = isL0 ? (t < T_IN) : (t >= 1);
    if (active) {
      f32x4 acc = {0.f, 0.f, 0.f, 0.f};
      const char* arow = HC + bb * HROW;
      #pragma unroll
      for (int kb = 0; kb < 32; ++kb)
        if (kb < nkbE)
          acc = mfma16(*(const f16x8*)(arow + ((lq * 16 + kb * 64) ^ aswz)), wreg[kb], acc);
      #pragma unroll
      for (int j = 0; j < 4; ++j) TTw[bb * 18 + lq * 4 + j] = acc[j];
      float ac[4];
      #pragma unroll
      for (int q = 0; q < 4; ++q)
        ac[q] = TTw[(4 * uu + q) * 18 + bb] + bL[(isL0 ? 0 : 64) + q * 16 + unitL];
      const int rowG = 16 * g + bb;
      if (isL0) {
        const float* xr = a.src + (size_t)rowG * (T_IN * F) + t * F;
        float4 x0 = *(const float4*)xr, x1 = *(const float4*)(xr + 4);
        float xv[8] = {x0.x, x0.y, x0.z, x0.w, x1.x, x1.y, x1.z, x1.w};
        #pragma unroll
        for (int q = 0; q < 4; ++q)
          #pragma unroll
          for (int k = 0; k < 8; ++k)
            ac[q] = fmaf(xv[k], WxL[(q * 16 + unitL) * 9 + k], ac[q]);
      }
      c01 = sigm(ac[1]) * c01 + sigm(ac[0]) * tanh_f(ac[2]);
      float h = sigm(ac[3]) * tanh_f(c01);
      unsigned short* hplane = (isL0 ? H0 : H1) + (size_t)nbuf * HBUF;
      st2_cg((void*)(hplane + (size_t)rowG * 512 + 16 * s + unitL),
             (unsigned)__half_as_ushort(__float2half_rn(h)));
    }
  };

  auto fcw = [&](char* HC, int g, int t) {
    const int pb_ = lane & 15, dd = (lane >> 4) & 1, hf = lane >> 5;
    const char* hp = HC + pb_ * HROW;
    const int fswz = (pb_ & 7) << 4;
    const float* wr = a.fcW + dd * 512 + hf * 256;
    float r = 0.f;
    #pragma unroll 8
    for (int j = 0; j < 32; ++j) {
      f16x8 v = *(const f16x8*)(hp + ((1024 + hf * 512 + j * 16) ^ fswz));
      float4 w0 = *(const float4*)(wr + j * 8);
      float4 w1 = *(const float4*)(wr + j * 8 + 4);
      r = fmaf((float)v[0], w0.x, r); r = fmaf((float)v[1], w0.y, r);
      r = fmaf((float)v[2], w0.z, r); r = fmaf((float)v[3], w0.w, r);
      r = fmaf((float)v[4], w1.x, r); r = fmaf((float)v[5], w1.y, r);
      r = fmaf((float)v[6], w1.z, r); r = fmaf((float)v[7], w1.w, r);
    }
    r += __shfl_xor(r, 32);
    if (lane < 32) {
      float pred = r + pWb[24 + dd];
      if (t == 0) pred = a.src[(size_t)(16 * g + pb_) * (T_IN * F) + 335 * F + dd * 2];
      p_lds[pb_ * 2 + dd] = pred;
      if (s == 0 && t > 0)
        a.out[(size_t)(16 * g + pb_) * (T_OUT * D_OUT) + (size_t)(t - 1) * D_OUT + dd] = pred;
    }
    const int bx = lane >> 2, j0 = (lane & 3) * 2;
    float pr0 = p_lds[bx * 2], pr1 = p_lds[bx * 2 + 1];
    x_lds[bx * 9 + j0]     = pWb[16 + j0]     + pr0 * pWb[j0 * 2]       + pr1 * pWb[j0 * 2 + 1];
    x_lds[bx * 9 + j0 + 1] = pWb[16 + j0 + 1] + pr0 * pWb[(j0 + 1) * 2] + pr1 * pWb[(j0 + 1) * 2 + 1];
  };

  auto decCompute1 = [&](char* HC, float& c01, int g, int t) {
    const int pA = t & 1;
    if (isL0) {
      f32x4 acc = {0.f, 0.f, 0.f, 0.f};
      const char* arow = HC + bb * HROW;
      #pragma unroll
      for (int kb = 0; kb < 16; ++kb)
        acc = mfma16(*(const f16x8*)(arow + ((lq * 16 + kb * 64) ^ aswz)), wreg[kb], acc);
      #pragma unroll
      for (int j = 0; j < 4; ++j) TTw[bb * 18 + lq * 4 + j] = acc[j];
    } else if (wid == 4) {
      fcw(HC, g, t);
    }
    __syncthreads();
    if (isL0) {
      float ac[4];
      #pragma unroll
      for (int q = 0; q < 4; ++q)
        ac[q] = TTw[(4 * uu + q) * 18 + bb] + bL[128 + q * 16 + unitL];
      #pragma unroll
      for (int q = 0; q < 4; ++q)
        #pragma unroll
        for (int k = 0; k < 8; ++k)
          ac[q] = fmaf(x_lds[bb * 9 + k], WxL[576 + (q * 16 + unitL) * 9 + k], ac[q]);
      c01 = sigm(ac[1]) * c01 + sigm(ac[0]) * tanh_f(ac[2]);
      float h = sigm(ac[3]) * tanh_f(c01);
      unsigned short* hplane = H0 + (size_t)(pA ^ 1) * HBUF;
      st2_cg((void*)(hplane + (size_t)(16 * g + bb) * 512 + 16 * s + unitL),
             (unsigned)__half_as_ushort(__float2half_rn(h)));
    }
  };

  auto decCompute2 = [&](char* HC, float& c01, int g, int t) {
    const int pA = t & 1;
    if (!isL0) {
      f32x4 acc = {0.f, 0.f, 0.f, 0.f};
      const char* arow = HC + bb * HROW;
      #pragma unroll
      for (int kb = 0; kb < 32; ++kb)
        acc = mfma16(*(const f16x8*)(arow + ((lq * 16 + kb * 64) ^ aswz)), wreg[kb], acc);
      #pragma unroll
      for (int j = 0; j < 4; ++j) TTw[bb * 18 + lq * 4 + j] = acc[j];
      float ac[4];
      #pragma unroll
      for (int q = 0; q < 4; ++q)
        ac[q] = TTw[(4 * uu + q) * 18 + bb] + bL[192 + q * 16 + unitL];
      c01 = sigm(ac[1]) * c01 + sigm(ac[0]) * tanh_f(ac[2]);
      float h = sigm(ac[3]) * tanh_f(c01);
      unsigned short* hplane = H1 + (size_t)pA * HBUF;
      st2_cg((void*)(hplane + (size_t)(16 * g + bb) * 512 + 16 * s + unitL),
             (unsigned)__half_as_ushort(__float2half_rn(h)));
    }
  };

  auto epiCompute = [&](char* HC, int g) {
    if (wid == 4 && s == 0) {
      const int pb_ = lane & 15, dd = (lane >> 4) & 1, hf = lane >> 5;
      const char* hp = HC + pb_ * HROW;
      const int fswz = (pb_ & 7) << 4;
      const float* wr = a.fcW + dd * 512 + hf * 256;
      float r = 0.f;
      #pragma unroll 8
      for (int j = 0; j < 32; ++j) {
        f16x8 v = *(const f16x8*)(hp + ((1024 + hf * 512 + j * 16) ^ fswz));
        float4 w0 = *(const float4*)(wr + j * 8);
        float4 w1 = *(const float4*)(wr + j * 8 + 4);
        r = fmaf((float)v[0], w0.x, r); r = fmaf((float)v[1], w0.y, r);
        r = fmaf((float)v[2], w0.z, r); r = fmaf((float)v[3], w0.w, r);
        r = fmaf((float)v[4], w1.x, r); r = fmaf((float)v[5], w1.y, r);
        r = fmaf((float)v[6], w1.z, r); r = fmaf((float)v[7], w1.w, r);
      }
      r += __shfl_xor(r, 32);
      if (lane < 32)
        a.out[(size_t)(16 * g + pb_) * (T_OUT * D_OUT) + (size_t)95 * D_OUT + dd] = r + pWb[24 + dd];
    }
  };

  // ================= prologue: prefetch EA(0) =================
  pollG(slotA, bsA);                       // trivial (slots zeroed)
  issue2(H0 + 0 * HBUF, H1 + 0 * HBUF, gA);

  // ================= encoder (pipelined dual-group) =================
  for (int t = 0; t <= T_IN; ++t) {
    const size_t bo = (size_t)(t & 1) * HBUF;
    // --- EA(t) ---
    write2(HCa);
    encCompute(HCa, cA, gA, t);
    pollG(slotB, bsB);
    issue2(H0 + bo, H1 + bo, gB);
    vw4(); __syncthreads(); pub(slotA, ++bsA);
    // --- EB(t) ---
    write2(HCb);
    encCompute(HCb, cB, gB, t);
    pollG(slotA, bsA);
    if (t < T_IN) {
      const size_t bn = (size_t)((t + 1) & 1) * HBUF;
      issue2(H0 + bn, H1 + bn, gA);
      vw4();
    } else {
      issue1(H1 + 1 * HBUF, gA);          // DA1(0): h1_A(final)
      vw2();
    }
    __syncthreads(); pub(slotB, ++bsB);
  }

  loadW(wD);   // weight swap; drained by next write1's vmcnt(0)

  // ================= decoder (4-phase pipelined) =================
  for (int t = 0; t < T_OUT; ++t) {
    const int pA = t & 1;
    // --- DA1(t) ---
    write1(HCa, 1024);
    decCompute1(HCa, cA, gA, t);
    pollG(slotB, bsB);
    issue1(H1 + (size_t)(pA ^ 1) * HBUF, gB);     // h1_B(t-1)
    vw2(); __syncthreads(); pub(slotA, ++bsA);
    // --- DB1(t) ---
    write1(HCb, 1024);
    decCompute1(HCb, cB, gB, t);
    pollG(slotA, bsA);
    issue1(H0 + (size_t)(pA ^ 1) * HBUF, gA);     // h0_A(t)
    vw2(); __syncthreads(); pub(slotB, ++bsB);
    // --- DA2(t) ---
    write1(HCa, 0);
    decCompute2(HCa, cA, gA, t);
    pollG(slotB, bsB);
    issue1(H0 + (size_t)(pA ^ 1) * HBUF, gB);     // h0_B(t)
    vw2(); __syncthreads(); pub(slotA, ++bsA);
    // --- DB2(t) ---
    write1(HCb, 0);
    decCompute2(HCb, cB, gB, t);
    pollG(slotA, bsA);
    issue1(H1 + (size_t)(((t + 1) & 1) ^ 1) * HBUF, gA);   // h1_A(t) (epilogue at t=95: buf 1)
    vw2(); __syncthreads(); pub(slotB, ++bsB);
  }

  // ================= epilogue =================
  // EPA: pf holds h1_A(95)
  write1(HCa, 1024);
  epiCompute(HCa, gA);
  pollG(slotB, bsB);
  issue1(H1 + 1 * HBUF, gB);
  // EPB:
  write1(HCb, 1024);
  epiCompute(HCb, gB);
}

extern "C" void kernel_launch(void* const* d_in, const int* in_sizes, int n_in,
                              void* d_out, int out_size, void* d_ws, size_t ws_size,
                              hipStream_t stream) {
  (void)in_sizes; (void)n_in; (void)out_size; (void)ws_size;
  const float* src   = (const float*)d_in[0];
  const float* eWih0 = (const float*)d_in[1];
  const float* eWhh0 = (const float*)d_in[2];
  const float* eb0   = (const float*)d_in[3];
  const float* eWih1 = (const float*)d_in[4];
  const float* eWhh1 = (const float*)d_in[5];
  const float* eb1   = (const float*)d_in[6];
  const float* dWih0 = (const float*)d_in[7];
  const float* dWhh0 = (const float*)d_in[8];
  const float* db0   = (const float*)d_in[9];
  const float* dWih1 = (const float*)d_in[10];
  const float* dWhh1 = (const float*)d_in[11];
  const float* db1   = (const float*)d_in[12];
  const float* fcW   = (const float*)d_in[13];
  const float* fcb   = (const float*)d_in[14];
  const float* pW    = (const float*)d_in[15];
  const float* pb    = (const float*)d_in[16];

  unsigned char* ws = (unsigned char*)d_ws;
  unsigned* cnt = (unsigned*)ws;                       // 4 KB slot barriers
  unsigned short* W = (unsigned short*)(ws + 4096);    // 12.6 MB fp16 tiled weights
  unsigned short* Hst = W + W_TOTAL;                   // 1 MB fp16 h-state

  (void)hipMemsetAsync(d_ws, 0, 4096, stream);
  (void)hipMemsetAsync((void*)Hst, 0, (size_t)4 * HBUF * sizeof(unsigned short), stream);

  hipLaunchKernelGGL(conv_kernel, dim3(W_TOTAL / 256), dim3(256), 0, stream,
                     eWhh0, eWih1, eWhh1, dWhh0, dWih1, dWhh1, W);

  Args a;
  a.src = src; a.eWih0 = eWih0; a.eb0 = eb0; a.eb1 = eb1;
  a.dWih0 = dWih0; a.db0 = db0; a.db1 = db1;
  a.fcW = fcW; a.fcb = fcb; a.pW = pW; a.pb = pb;
  a.W = W; a.Hst = Hst; a.out = (float*)d_out; a.cnt = cnt;

  const size_t smem_bytes = 65536 + (2304 + 32 + 144 + 1152 + 256 + 32) * sizeof(float);
  hipLaunchKernelGGL(forecast_kernel, dim3((NGRP / 2) * WPG), dim3(NT), smem_bytes, stream, a);
}